// Round 6
// baseline (3933.907 us; speedup 1.0000x reference)
//
#include <hip/hip_runtime.h>
#include <cstdint>
#include <cstddef>

#define B_    256
#define W_    41
#define D_    512
#define K_    4096
#define L_    8
#define NROWS (B_ * W_)            // 10496
#define QOUT_ELEMS (NROWS * D_)    // 5373952

typedef _Float16 f16;
typedef __attribute__((ext_vector_type(4))) _Float16 f16x4;
typedef __attribute__((ext_vector_type(8))) _Float16 f16x8;
typedef __attribute__((ext_vector_type(4))) float f32x4;

// ---------------- workspace layout (bytes) ----------------
#define WS_R        0u
#define WS_ROWNORM  21495808u
#define WS_KEYS     21537792u
#define WS_LOSS     21621760u
#define WS_RH       21705728u
#define WS_EH       32453632u
#define WS_CCNT     66008064u           // NROWS int counters (42 KB)
#define WS_CLIST    66073600u           // NROWS * CAP * 4 B = 43 MB
#define WS_NEEDED   151991296u

#define CAP 1024

// -------- init: residual = x, rowNorm, arm keys + candidate counters ------
__global__ __launch_bounds__(256)
void rq_init(const float* __restrict__ x, float* __restrict__ R,
             float* __restrict__ rowNorm, unsigned long long* __restrict__ keys,
             f16* __restrict__ Rh, int* __restrict__ candCount)
{
    const int wave = threadIdx.x >> 6;
    const int lane = threadIdx.x & 63;
    const int n = blockIdx.x * 4 + wave;
    const float4* xp = (const float4*)(x + (size_t)n * D_);
    float4* rp = (float4*)(R + (size_t)n * D_);
    double asum = 0.0;
#pragma unroll
    for (int u = 0; u < 2; ++u) {
        const int idx = u * 64 + lane;
        float4 v = xp[idx];
        rp[idx] = v;
        if (Rh) {
            f16x4 hv; hv[0]=(_Float16)v.x; hv[1]=(_Float16)v.y;
            hv[2]=(_Float16)v.z; hv[3]=(_Float16)v.w;
            *(f16x4*)(Rh + (size_t)n * D_ + idx * 4) = hv;
        }
        asum += (double)v.x * v.x + (double)v.y * v.y
              + (double)v.z * v.z + (double)v.w * v.w;
    }
#pragma unroll
    for (int off = 32; off > 0; off >>= 1)
        asum += __shfl_down(asum, off, 64);
    if (lane == 0) {
        rowNorm[n] = (float)asum;
        keys[n] = 0xFFFFFFFFFFFFFFFFull;
        if (candCount) candCount[n] = 0;
    }
}

// -------- codebook fp32 -> f16 (all 8 layers, once) ----------
__global__ __launch_bounds__(256)
void rq_cvt_eh(const float* __restrict__ cb, f16* __restrict__ Eh)
{
    const size_t i = ((size_t)blockIdx.x * 256 + threadIdx.x) * 4;
    float4 v = *(const float4*)(cb + i);
    f16x4 h; h[0]=(_Float16)v.x; h[1]=(_Float16)v.y;
    h[2]=(_Float16)v.z; h[3]=(_Float16)v.w;
    *(f16x4*)(Eh + i) = h;
}

// -------- MFMA screen GEMM + fused candidate emission ----------
// S_acc[n][k] = Rh[n]·Eh[k] (f16 in, f32 acc) computed but NEVER stored.
// Per 128-col block: row-local max via shfl butterfly + LDS cross-wave
// combine; every col with S_acc >= blockRowMax - tau is appended to the
// row's candidate list. Block-relative threshold gives a SUPERSET of the
// global-threshold candidate set (blockmax <= globalmax), and the true
// argmin winner provably passes its own block's threshold:
//   blockmax_b - S_acc[winner] <= (S_chain[m]-S_chain[w]) + 2*e_f16
//     <= ulp(An) + 2*e_f16 (~3.1e-4) < tau = sqrt(An)*2e-5 + 3e-4.
// Exactness restored by rq_select's verbatim fp32-chain rescore.
#define GLDK 40
__global__ __launch_bounds__(256)
void rq_screen_gemm(const f16* __restrict__ Rh, const f16* __restrict__ Eh,
                    const float* __restrict__ rowNorm,
                    int* __restrict__ candCount, int* __restrict__ candList)
{
    __shared__ _Float16 At[128 * GLDK];   // 10240 B
    __shared__ _Float16 Bt[128 * GLDK];   // 10240 B
    __shared__ float rmaxW[2][128];       // per col-half row max
    __shared__ float tauS[128];

    const int t    = threadIdx.x;
    const int lane = t & 63;
    const int wid  = t >> 6;
    const int wr   = (wid >> 1) * 64;     // wave quadrant row
    const int wc   = (wid & 1) * 64;      // wave quadrant col
    const int rowBase = blockIdx.y * 128;
    const int colBase = blockIdx.x * 128;

    const int r16 = lane & 15;
    const int ks  = lane >> 4;            // k-slot 0..3

    const int sr0 = t >> 2,         sk0 = (t & 3) * 8;
    const int sr1 = (t + 256) >> 2, sk1 = (t & 3) * 8;

    if (t < 128)
        tauS[t] = sqrtf(rowNorm[rowBase + t]) * 2.0e-5f + 3.0e-4f;

    const f16* Ag = Rh + (size_t)rowBase * D_;
    const f16* Bg = Eh + (size_t)colBase * D_;

    f32x4 acc[4][4];
#pragma unroll
    for (int i = 0; i < 4; ++i)
#pragma unroll
        for (int j = 0; j < 4; ++j) acc[i][j] = (f32x4){0.f, 0.f, 0.f, 0.f};

    for (int dt = 0; dt < D_; dt += 32) {
        const float4 a0 = *(const float4*)(Ag + (size_t)sr0 * D_ + dt + sk0);
        const float4 a1 = *(const float4*)(Ag + (size_t)sr1 * D_ + dt + sk1);
        const float4 b0 = *(const float4*)(Bg + (size_t)sr0 * D_ + dt + sk0);
        const float4 b1 = *(const float4*)(Bg + (size_t)sr1 * D_ + dt + sk1);
        __syncthreads();
        *(float4*)&At[sr0 * GLDK + sk0] = a0;
        *(float4*)&At[sr1 * GLDK + sk1] = a1;
        *(float4*)&Bt[sr0 * GLDK + sk0] = b0;
        *(float4*)&Bt[sr1 * GLDK + sk1] = b1;
        __syncthreads();

        f16x8 af[4], bf[4];
#pragma unroll
        for (int mi = 0; mi < 4; ++mi)
            af[mi] = *(const f16x8*)&At[(wr + mi * 16 + r16) * GLDK + ks * 8];
#pragma unroll
        for (int ni = 0; ni < 4; ++ni)
            bf[ni] = *(const f16x8*)&Bt[(wc + ni * 16 + r16) * GLDK + ks * 8];
#pragma unroll
        for (int mi = 0; mi < 4; ++mi)
#pragma unroll
            for (int ni = 0; ni < 4; ++ni)
                acc[mi][ni] = __builtin_amdgcn_mfma_f32_16x16x32_f16(
                    af[mi], bf[ni], acc[mi][ni], 0, 0, 0);
    }

    // ---- fused epilogue: row max (this block's 128 cols) + emission ----
    // C/D layout (m89): reg i of lane l -> row (l>>4)*4+i, col l&15
    const int g = lane >> 4;

    float vmax[4][4];
#pragma unroll
    for (int mi = 0; mi < 4; ++mi)
#pragma unroll
        for (int i = 0; i < 4; ++i) {
            float m0 = fmaxf(acc[mi][0][i], acc[mi][1][i]);
            float m1 = fmaxf(acc[mi][2][i], acc[mi][3][i]);
            vmax[mi][i] = fmaxf(m0, m1);
        }
#pragma unroll
    for (int off = 1; off < 16; off <<= 1)
#pragma unroll
        for (int mi = 0; mi < 4; ++mi)
#pragma unroll
            for (int i = 0; i < 4; ++i)
                vmax[mi][i] = fmaxf(vmax[mi][i],
                                    __shfl_xor(vmax[mi][i], off, 64));
    if (r16 == 0) {
#pragma unroll
        for (int mi = 0; mi < 4; ++mi)
#pragma unroll
            for (int i = 0; i < 4; ++i)
                rmaxW[wid & 1][wr + mi * 16 + g * 4 + i] = vmax[mi][i];
    }
    __syncthreads();

#pragma unroll
    for (int mi = 0; mi < 4; ++mi)
#pragma unroll
        for (int i = 0; i < 4; ++i) {
            const int lrow = wr + mi * 16 + g * 4 + i;
            const float thr = fmaxf(rmaxW[0][lrow], rmaxW[1][lrow])
                              - tauS[lrow];
            const int grow = rowBase + lrow;
#pragma unroll
            for (int ni = 0; ni < 4; ++ni) {
                if (acc[mi][ni][i] >= thr) {
                    const int pos = atomicAdd(&candCount[grow], 1);
                    if (pos < CAP)
                        candList[(size_t)grow * CAP + pos] =
                            colBase + wc + ni * 16 + r16;
                }
            }
        }
}

// -------- exact rescore helper: verbatim ascending-d fp32 fmaf chain ------
__device__ __forceinline__ unsigned long long
rescore_key(const float4* __restrict__ a4, const float* __restrict__ E,
            int col, float An)
{
    const float4* b4 = (const float4*)(E + (size_t)col * D_);
    float acc = 0.f;
    for (int d = 0; d < 128; ++d) {
        const float4 a = a4[d], b = b4[d];
        acc = fmaf(a.x, b.x, acc); acc = fmaf(a.y, b.y, acc);
        acc = fmaf(a.z, b.z, acc); acc = fmaf(a.w, b.w, acc);
    }
    const float c = __fsub_rn(An, 2.0f * acc);
    return ((unsigned long long)__float_as_uint(c) << 32) | (unsigned int)col;
}

// -------- select: rescore the candidate list, one wave per row ----------
// key = (bits(c)<<32)|k; u64 min == lexicographic (c,k) min == np.argmin
// first-index tie rule. Candidate list is a superset of all possible
// winners (see rq_screen_gemm), so min over exact keys is exact.
// Overflow (count > CAP, practically never): exact full scan of the row.
__global__ __launch_bounds__(256)
void rq_select(const int* __restrict__ candCount,
               const int* __restrict__ candList,
               const float* __restrict__ R, const float* __restrict__ E,
               const float* __restrict__ rowNorm,
               unsigned long long* __restrict__ keys)
{
    const int lane = threadIdx.x & 63;
    const int wv   = threadIdx.x >> 6;
    const int row  = blockIdx.x * 4 + wv;
    const float An = rowNorm[row];
    const float4* a4 = (const float4*)(R + (size_t)row * D_);

    unsigned long long best = 0xFFFFFFFFFFFFFFFFull;
    const int cnt = candCount[row];

    if (cnt <= CAP) {
        const int* cl = candList + (size_t)row * CAP;
        for (int base = 0; base < cnt; base += 64) {
            const int ci = base + lane;
            if (ci < cnt) {
                const unsigned long long k = rescore_key(a4, E, cl[ci], An);
                if (k < best) best = k;
            }
        }
    } else {
        // correctness-safe fallback: exact scan of all K cols
        for (int col = lane; col < K_; col += 64) {
            const unsigned long long k = rescore_key(a4, E, col, An);
            if (k < best) best = k;
        }
    }
#pragma unroll
    for (int mm = 1; mm < 64; mm <<= 1) {
        const unsigned long long o = __shfl_xor(best, mm, 64);
        if (o < best) best = o;
    }
    if (lane == 0) keys[row] = best;   // single owner: plain write
}

// -------- FALLBACK distance GEMM + argmin (round-0 verbatim, proven) ------
#define FBM 128
#define FBN 128
#define FBKD 8
__global__ __launch_bounds__(256)
void rq_dist_argmin(const float* __restrict__ R, const float* __restrict__ E,
                    const float* __restrict__ rowNorm,
                    unsigned long long* __restrict__ keys)
{
    __shared__ float As[FBKD][FBM];
    __shared__ float Bs[FBKD][FBN];

    const int t  = threadIdx.x;
    const int tx = t & 15;
    const int ty = t >> 4;
    const int rowBase = blockIdx.y * FBM;
    const int colBase = blockIdx.x * FBN;

    const int lm   = t >> 1;
    const int lseg = (t & 1) * 4;

    const float* Aptr = R + (size_t)(rowBase + lm) * D_ + lseg;
    const float* Bptr = E + (size_t)(colBase + lm) * D_ + lseg;

    float acc[8][8];
#pragma unroll
    for (int i = 0; i < 8; ++i)
#pragma unroll
        for (int j = 0; j < 8; ++j) acc[i][j] = 0.0f;

    for (int dt = 0; dt < D_; dt += FBKD) {
        const float4 av = *(const float4*)(Aptr + dt);
        const float4 bv = *(const float4*)(Bptr + dt);
        __syncthreads();
        As[lseg + 0][lm] = av.x; As[lseg + 1][lm] = av.y;
        As[lseg + 2][lm] = av.z; As[lseg + 3][lm] = av.w;
        Bs[lseg + 0][lm] = bv.x; Bs[lseg + 1][lm] = bv.y;
        Bs[lseg + 2][lm] = bv.z; Bs[lseg + 3][lm] = bv.w;
        __syncthreads();
#pragma unroll
        for (int dd = 0; dd < FBKD; ++dd) {
            float a[8], b[8];
            *(float4*)&a[0] = *(const float4*)&As[dd][ty * 4];
            *(float4*)&a[4] = *(const float4*)&As[dd][ty * 4 + 64];
            *(float4*)&b[0] = *(const float4*)&Bs[dd][tx * 4];
            *(float4*)&b[4] = *(const float4*)&Bs[dd][tx * 4 + 64];
#pragma unroll
            for (int i = 0; i < 8; ++i)
#pragma unroll
                for (int j = 0; j < 8; ++j)
                    acc[i][j] = fmaf(a[i], b[j], acc[i][j]);
        }
    }

#pragma unroll
    for (int i = 0; i < 8; ++i) {
        const int rl = ty * 4 + (i & 3) + ((i >= 4) ? 64 : 0);
        const float An = rowNorm[rowBase + rl];
        unsigned long long best = 0xFFFFFFFFFFFFFFFFull;
#pragma unroll
        for (int j = 0; j < 8; ++j) {
            const int col = colBase + tx * 4 + (j & 3) + ((j >= 4) ? 64 : 0);
            const float c = __fsub_rn(An, 2.0f * acc[i][j]);
            const unsigned long long key =
                ((unsigned long long)__float_as_uint(c) << 32)
                | (unsigned int)col;
            if (key < best) best = key;
        }
#pragma unroll
        for (int m = 1; m < 16; m <<= 1) {
            const unsigned long long o = __shfl_xor(best, m, 64);
            if (o < best) best = o;
        }
        if (tx == 0)
            atomicMin(&keys[rowBase + rl], best);
    }
}

// -------- per-layer update: STE epilogue, exact fp32 replication ----------
__global__ __launch_bounds__(256)
void rq_update(float* __restrict__ R, const float* __restrict__ E,
               unsigned long long* __restrict__ keys,
               float* __restrict__ qout, float* __restrict__ idxOut,
               float* __restrict__ rowNorm, double* __restrict__ lossPartial,
               int layer, f16* __restrict__ Rh, int* __restrict__ candCount)
{
    const int wave = threadIdx.x >> 6;
    const int lane = threadIdx.x & 63;
    const int n = blockIdx.x * 4 + wave;
    const unsigned long long key = keys[n];
    const int k = (int)(key & 0xFFFFFFFFull);

    const float4* ep = (const float4*)(E + (size_t)k * D_);
    float4* rp = (float4*)(R + (size_t)n * D_);
    float4* qp = (float4*)(qout + (size_t)n * D_);

    double lsum = 0.0, asum = 0.0;
#pragma unroll
    for (int u = 0; u < 2; ++u) {
        const int idx = u * 64 + lane;
        float4 r4 = rp[idx];
        float4 q4 = ep[idx];
        float4 o4 = (layer == 0) ? make_float4(0.f, 0.f, 0.f, 0.f) : qp[idx];
        float rnew[4], qo[4];
        float rr[4] = {r4.x, r4.y, r4.z, r4.w};
        float qq[4] = {q4.x, q4.y, q4.z, q4.w};
        float oo[4] = {o4.x, o4.y, o4.z, o4.w};
#pragma unroll
        for (int c = 0; c < 4; ++c) {
            const float d1  = __fsub_rn(qq[c], rr[c]);
            const float qst = __fadd_rn(rr[c], d1);
            rnew[c] = __fsub_rn(rr[c], qst);
            qo[c]   = __fadd_rn(oo[c], qst);
            lsum += (double)d1 * (double)d1;
            asum += (double)rnew[c] * (double)rnew[c];
        }
        rp[idx] = make_float4(rnew[0], rnew[1], rnew[2], rnew[3]);
        qp[idx] = make_float4(qo[0], qo[1], qo[2], qo[3]);
        if (Rh && layer < L_ - 1) {
            f16x4 hv; hv[0]=(_Float16)rnew[0]; hv[1]=(_Float16)rnew[1];
            hv[2]=(_Float16)rnew[2]; hv[3]=(_Float16)rnew[3];
            *(f16x4*)(Rh + (size_t)n * D_ + idx * 4) = hv;
        }
    }
#pragma unroll
    for (int off = 32; off > 0; off >>= 1) {
        lsum += __shfl_down(lsum, off, 64);
        asum += __shfl_down(asum, off, 64);
    }
    if (lane == 0) {
        rowNorm[n] = (float)asum;
        keys[n] = 0xFFFFFFFFFFFFFFFFull;   // re-arm (fallback path needs it)
        if (candCount) candCount[n] = 0;   // re-arm candidate counter
        lossPartial[n] = (layer == 0) ? lsum : (lossPartial[n] + lsum);
        idxOut[(size_t)n * L_ + layer] = (float)k;
    }
}

// -------- finalize: sum 10496 per-row partials, scale ----------
__global__ __launch_bounds__(256)
void rq_finalize(float* __restrict__ lossOut,
                 const double* __restrict__ lossPartial)
{
    __shared__ double ws[4];
    const int t = threadIdx.x;
    double s = 0.0;
    for (int i = t; i < NROWS; i += 256) s += lossPartial[i];
#pragma unroll
    for (int off = 32; off > 0; off >>= 1)
        s += __shfl_down(s, off, 64);
    if ((t & 63) == 0) ws[t >> 6] = s;
    __syncthreads();
    if (t == 0) {
        double tot = ws[0] + ws[1] + ws[2] + ws[3];
        *lossOut = (float)(0.25 * tot / (double)QOUT_ELEMS);
    }
}

extern "C" void kernel_launch(void* const* d_in, const int* in_sizes, int n_in,
                              void* d_out, int out_size, void* d_ws, size_t ws_size,
                              hipStream_t stream)
{
    const float* x  = (const float*)d_in[0];
    const float* cb = (const float*)d_in[1];
    float* out = (float*)d_out;
    char* ws = (char*)d_ws;

    float* R = (float*)(ws + WS_R);
    float* rowNorm = (float*)(ws + WS_ROWNORM);
    unsigned long long* keys = (unsigned long long*)(ws + WS_KEYS);
    double* lossPartial = (double*)(ws + WS_LOSS);

    const bool fast = (ws_size >= (size_t)WS_NEEDED);
    f16* Rh = fast ? (f16*)(ws + WS_RH) : (f16*)nullptr;
    f16* Eh = fast ? (f16*)(ws + WS_EH) : (f16*)nullptr;
    int* candCount = fast ? (int*)(ws + WS_CCNT) : (int*)nullptr;
    int* candList  = fast ? (int*)(ws + WS_CLIST) : (int*)nullptr;

    float* idxOut = out + QOUT_ELEMS + 1;

    rq_init<<<NROWS / 4, 256, 0, stream>>>(x, R, rowNorm, keys, Rh, candCount);
    if (fast)
        rq_cvt_eh<<<(L_ * K_ * D_) / (4 * 256), 256, 0, stream>>>(cb, Eh);

    for (int l = 0; l < L_; ++l) {
        const float* E = cb + (size_t)l * K_ * D_;
        if (fast) {
            dim3 grid(K_ / 128, NROWS / 128);   // (32, 82)
            rq_screen_gemm<<<grid, 256, 0, stream>>>(
                Rh, Eh + (size_t)l * K_ * D_, rowNorm, candCount, candList);
            rq_select<<<NROWS / 4, 256, 0, stream>>>(candCount, candList,
                                                     R, E, rowNorm, keys);
        } else {
            dim3 grid(K_ / FBN, NROWS / FBM);
            rq_dist_argmin<<<grid, 256, 0, stream>>>(R, E, rowNorm, keys);
        }
        rq_update<<<NROWS / 4, 256, 0, stream>>>(R, E, keys, out, idxOut,
                                                 rowNorm, lossPartial, l,
                                                 Rh, candCount);
    }
    rq_finalize<<<1, 256, 0, stream>>>(out + QOUT_ELEMS, lossPartial);
}

// Round 7
// 2544.034 us; speedup vs baseline: 1.5463x; 1.5463x over previous
//
#include <hip/hip_runtime.h>
#include <cstdint>
#include <cstddef>

#define B_    256
#define W_    41
#define D_    512
#define K_    4096
#define L_    8
#define NROWS (B_ * W_)            // 10496
#define QOUT_ELEMS (NROWS * D_)    // 5373952

typedef _Float16 f16;
typedef __attribute__((ext_vector_type(4))) _Float16 f16x4;
typedef __attribute__((ext_vector_type(8))) _Float16 f16x8;
typedef __attribute__((ext_vector_type(4))) float f32x4;

// ---------------- workspace layout (bytes) ----------------
#define WS_R        0u            // 21,495,808
#define WS_ROWNORM  21495808u     //     41,984
#define WS_KEYS     21537792u     //     83,968
#define WS_LOSS     21621760u     //     83,968
#define WS_RH       21705728u     // 10,747,904
#define WS_EH       32453632u     // 33,554,432
#define WS_CCNT     66008064u     //     41,984
#define WS_BMAX     66050048u     //  1,343,488 (NROWS * 32 f32)
#define WS_CLIST    67393536u     // 21,495,808 (NROWS * CAP u64)
#define WS_NEEDED   88889344u

#define CAP 256

// -------- init: residual = x, rowNorm, arm keys + candidate counters ------
__global__ __launch_bounds__(256)
void rq_init(const float* __restrict__ x, float* __restrict__ R,
             float* __restrict__ rowNorm, unsigned long long* __restrict__ keys,
             f16* __restrict__ Rh, int* __restrict__ candCount)
{
    const int wave = threadIdx.x >> 6;
    const int lane = threadIdx.x & 63;
    const int n = blockIdx.x * 4 + wave;
    const float4* xp = (const float4*)(x + (size_t)n * D_);
    float4* rp = (float4*)(R + (size_t)n * D_);
    double asum = 0.0;
#pragma unroll
    for (int u = 0; u < 2; ++u) {
        const int idx = u * 64 + lane;
        float4 v = xp[idx];
        rp[idx] = v;
        if (Rh) {
            f16x4 hv; hv[0]=(_Float16)v.x; hv[1]=(_Float16)v.y;
            hv[2]=(_Float16)v.z; hv[3]=(_Float16)v.w;
            *(f16x4*)(Rh + (size_t)n * D_ + idx * 4) = hv;
        }
        asum += (double)v.x * v.x + (double)v.y * v.y
              + (double)v.z * v.z + (double)v.w * v.w;
    }
#pragma unroll
    for (int off = 32; off > 0; off >>= 1)
        asum += __shfl_down(asum, off, 64);
    if (lane == 0) {
        rowNorm[n] = (float)asum;
        keys[n] = 0xFFFFFFFFFFFFFFFFull;
        if (candCount) candCount[n] = 0;
    }
}

// -------- codebook fp32 -> f16 (all 8 layers, once) ----------
__global__ __launch_bounds__(256)
void rq_cvt_eh(const float* __restrict__ cb, f16* __restrict__ Eh)
{
    const size_t i = ((size_t)blockIdx.x * 256 + threadIdx.x) * 4;
    float4 v = *(const float4*)(cb + i);
    f16x4 h; h[0]=(_Float16)v.x; h[1]=(_Float16)v.y;
    h[2]=(_Float16)v.z; h[3]=(_Float16)v.w;
    *(f16x4*)(Eh + i) = h;
}

// -------- MFMA screen GEMM + fused candidate emission ----------
// S_acc[n][k] = Rh[n]·Eh[k] (f16 in, f32 acc), never stored densely.
// Per 128-col block: row max -> bmax[row][blk] (plain store) AND every col
// with S_acc >= blockmax - tau appended to the row list as (bits(S)<<32|col).
// The true argmin winner always passes its own block's cut:
//   blockmax - S_acc[winner] <= (chain spread) + 2*e_f16 < tau
//   tau = sqrt(An)*2e-5 + 3e-4.
// rq_select_update re-filters by GLOBAL max (from bmax) with the same tau,
// then restores exactness with the verbatim fp32-chain rescore.
#define GLDK 40
__global__ __launch_bounds__(256)
void rq_screen_gemm(const f16* __restrict__ Rh, const f16* __restrict__ Eh,
                    const float* __restrict__ rowNorm,
                    int* __restrict__ candCount,
                    unsigned long long* __restrict__ candList,
                    float* __restrict__ bmax)
{
    __shared__ _Float16 At[128 * GLDK];   // 10240 B
    __shared__ _Float16 Bt[128 * GLDK];   // 10240 B
    __shared__ float rmaxW[2][128];       // per col-half row max
    __shared__ float tauS[128];

    const int t    = threadIdx.x;
    const int lane = t & 63;
    const int wid  = t >> 6;
    const int wr   = (wid >> 1) * 64;     // wave quadrant row
    const int wc   = (wid & 1) * 64;      // wave quadrant col
    const int rowBase = blockIdx.y * 128;
    const int colBase = blockIdx.x * 128;

    const int r16 = lane & 15;
    const int ks  = lane >> 4;            // k-slot 0..3

    const int sr0 = t >> 2,         sk0 = (t & 3) * 8;
    const int sr1 = (t + 256) >> 2, sk1 = (t & 3) * 8;

    if (t < 128)
        tauS[t] = sqrtf(rowNorm[rowBase + t]) * 2.0e-5f + 3.0e-4f;

    const f16* Ag = Rh + (size_t)rowBase * D_;
    const f16* Bg = Eh + (size_t)colBase * D_;

    f32x4 acc[4][4];
#pragma unroll
    for (int i = 0; i < 4; ++i)
#pragma unroll
        for (int j = 0; j < 4; ++j) acc[i][j] = (f32x4){0.f, 0.f, 0.f, 0.f};

    for (int dt = 0; dt < D_; dt += 32) {
        const float4 a0 = *(const float4*)(Ag + (size_t)sr0 * D_ + dt + sk0);
        const float4 a1 = *(const float4*)(Ag + (size_t)sr1 * D_ + dt + sk1);
        const float4 b0 = *(const float4*)(Bg + (size_t)sr0 * D_ + dt + sk0);
        const float4 b1 = *(const float4*)(Bg + (size_t)sr1 * D_ + dt + sk1);
        __syncthreads();
        *(float4*)&At[sr0 * GLDK + sk0] = a0;
        *(float4*)&At[sr1 * GLDK + sk1] = a1;
        *(float4*)&Bt[sr0 * GLDK + sk0] = b0;
        *(float4*)&Bt[sr1 * GLDK + sk1] = b1;
        __syncthreads();

        f16x8 af[4], bf[4];
#pragma unroll
        for (int mi = 0; mi < 4; ++mi)
            af[mi] = *(const f16x8*)&At[(wr + mi * 16 + r16) * GLDK + ks * 8];
#pragma unroll
        for (int ni = 0; ni < 4; ++ni)
            bf[ni] = *(const f16x8*)&Bt[(wc + ni * 16 + r16) * GLDK + ks * 8];
#pragma unroll
        for (int mi = 0; mi < 4; ++mi)
#pragma unroll
            for (int ni = 0; ni < 4; ++ni)
                acc[mi][ni] = __builtin_amdgcn_mfma_f32_16x16x32_f16(
                    af[mi], bf[ni], acc[mi][ni], 0, 0, 0);
    }

    // ---- epilogue: per-row block max + candidate emission ----
    // C/D layout (m89): reg i of lane l -> row (l>>4)*4+i, col l&15
    const int g = lane >> 4;

    float vmax[4][4];
#pragma unroll
    for (int mi = 0; mi < 4; ++mi)
#pragma unroll
        for (int i = 0; i < 4; ++i) {
            float m0 = fmaxf(acc[mi][0][i], acc[mi][1][i]);
            float m1 = fmaxf(acc[mi][2][i], acc[mi][3][i]);
            vmax[mi][i] = fmaxf(m0, m1);
        }
#pragma unroll
    for (int off = 1; off < 16; off <<= 1)
#pragma unroll
        for (int mi = 0; mi < 4; ++mi)
#pragma unroll
            for (int i = 0; i < 4; ++i)
                vmax[mi][i] = fmaxf(vmax[mi][i],
                                    __shfl_xor(vmax[mi][i], off, 64));
    if (r16 == 0) {
#pragma unroll
        for (int mi = 0; mi < 4; ++mi)
#pragma unroll
            for (int i = 0; i < 4; ++i)
                rmaxW[wid & 1][wr + mi * 16 + g * 4 + i] = vmax[mi][i];
    }
    __syncthreads();

    if (t < 128)   // publish per-block row max for the global filter
        bmax[(size_t)(rowBase + t) * 32 + blockIdx.x]
            = fmaxf(rmaxW[0][t], rmaxW[1][t]);

#pragma unroll
    for (int mi = 0; mi < 4; ++mi)
#pragma unroll
        for (int i = 0; i < 4; ++i) {
            const int lrow = wr + mi * 16 + g * 4 + i;
            const float thr = fmaxf(rmaxW[0][lrow], rmaxW[1][lrow])
                              - tauS[lrow];
            const int grow = rowBase + lrow;
#pragma unroll
            for (int ni = 0; ni < 4; ++ni) {
                const float sv = acc[mi][ni][i];
                if (sv >= thr) {
                    const int pos = atomicAdd(&candCount[grow], 1);
                    if (pos < CAP)
                        candList[(size_t)grow * CAP + pos] =
                            ((unsigned long long)__float_as_uint(sv) << 32)
                            | (unsigned int)(colBase + wc + ni * 16 + r16);
                }
            }
        }
}

// -------- exact rescore helper: verbatim ascending-d fp32 fmaf chain ------
__device__ __forceinline__ unsigned long long
rescore_key(const float4* __restrict__ a4, const float* __restrict__ E,
            int col, float An)
{
    const float4* b4 = (const float4*)(E + (size_t)col * D_);
    float acc = 0.f;
    for (int d = 0; d < 128; ++d) {
        const float4 a = a4[d], b = b4[d];
        acc = fmaf(a.x, b.x, acc); acc = fmaf(a.y, b.y, acc);
        acc = fmaf(a.z, b.z, acc); acc = fmaf(a.w, b.w, acc);
    }
    const float c = __fsub_rn(An, 2.0f * acc);
    return ((unsigned long long)__float_as_uint(c) << 32) | (unsigned int)col;
}

// -------- fused select + STE update: one wave per row ----------
// (1) gmax = max over the row's 32 per-block maxes; global filter
//     S >= gmax - tau keeps the true winner (same bound as screen's cut).
// (2) exact rescore of the ~2-6 survivors (verbatim fp32 chain);
//     u64 (c,k) min == np.argmin first-index tie rule.
// (3) STE epilogue identical to the proven rq_update (R row cache-hot).
__global__ __launch_bounds__(256)
void rq_select_update(const int* __restrict__ candCountIn,
                      int* __restrict__ candCount,
                      const unsigned long long* __restrict__ candList,
                      const float* __restrict__ bmax,
                      float* __restrict__ R, const float* __restrict__ E,
                      float* __restrict__ qout, float* __restrict__ idxOut,
                      float* __restrict__ rowNorm,
                      double* __restrict__ lossPartial,
                      int layer, f16* __restrict__ Rh)
{
    const int lane = threadIdx.x & 63;
    const int wv   = threadIdx.x >> 6;
    const int n    = blockIdx.x * 4 + wv;
    const float An = rowNorm[n];
    const float4* a4 = (const float4*)(R + (size_t)n * D_);

    // global row max from the 32 per-block maxes
    float gm = bmax[(size_t)n * 32 + (lane & 31)];
#pragma unroll
    for (int off = 1; off < 32; off <<= 1)
        gm = fmaxf(gm, __shfl_xor(gm, off, 64));
    const float tau = sqrtf(An) * 2.0e-5f + 3.0e-4f;
    const float thr = gm - tau;

    unsigned long long best = 0xFFFFFFFFFFFFFFFFull;
    const int cnt = candCountIn[n];

    if (cnt <= CAP) {
        const unsigned long long* cl = candList + (size_t)n * CAP;
        for (int base = 0; base < cnt; base += 64) {
            const int ci = base + lane;
            if (ci < cnt) {
                const unsigned long long e = cl[ci];
                const float sv = __uint_as_float((unsigned int)(e >> 32));
                if (sv >= thr) {
                    const int col = (int)(e & 0xFFFFFFFFull);
                    const unsigned long long k = rescore_key(a4, E, col, An);
                    if (k < best) best = k;
                }
            }
        }
    } else {
        // correctness-safe fallback: exact scan of all K cols
        for (int col = lane; col < K_; col += 64) {
            const unsigned long long k = rescore_key(a4, E, col, An);
            if (k < best) best = k;
        }
    }
#pragma unroll
    for (int mm = 1; mm < 64; mm <<= 1) {
        const unsigned long long o = __shfl_xor(best, mm, 64);
        if (o < best) best = o;
    }
    const int k = (int)(best & 0xFFFFFFFFull);

    // ---- STE update (verbatim exact fp32 replication) ----
    const float4* ep = (const float4*)(E + (size_t)k * D_);
    float4* rp = (float4*)(R + (size_t)n * D_);
    float4* qp = (float4*)(qout + (size_t)n * D_);

    double lsum = 0.0, asum = 0.0;
#pragma unroll
    for (int u = 0; u < 2; ++u) {
        const int idx = u * 64 + lane;
        float4 r4 = rp[idx];
        float4 q4 = ep[idx];
        float4 o4 = (layer == 0) ? make_float4(0.f, 0.f, 0.f, 0.f) : qp[idx];
        float rnew[4], qo[4];
        float rr[4] = {r4.x, r4.y, r4.z, r4.w};
        float qq[4] = {q4.x, q4.y, q4.z, q4.w};
        float oo[4] = {o4.x, o4.y, o4.z, o4.w};
#pragma unroll
        for (int c = 0; c < 4; ++c) {
            const float d1  = __fsub_rn(qq[c], rr[c]);
            const float qst = __fadd_rn(rr[c], d1);
            rnew[c] = __fsub_rn(rr[c], qst);
            qo[c]   = __fadd_rn(oo[c], qst);
            lsum += (double)d1 * (double)d1;
            asum += (double)rnew[c] * (double)rnew[c];
        }
        rp[idx] = make_float4(rnew[0], rnew[1], rnew[2], rnew[3]);
        qp[idx] = make_float4(qo[0], qo[1], qo[2], qo[3]);
        if (layer < L_ - 1) {
            f16x4 hv; hv[0]=(_Float16)rnew[0]; hv[1]=(_Float16)rnew[1];
            hv[2]=(_Float16)rnew[2]; hv[3]=(_Float16)rnew[3];
            *(f16x4*)(Rh + (size_t)n * D_ + idx * 4) = hv;
        }
    }
#pragma unroll
    for (int off = 32; off > 0; off >>= 1) {
        lsum += __shfl_down(lsum, off, 64);
        asum += __shfl_down(asum, off, 64);
    }
    if (lane == 0) {
        rowNorm[n] = (float)asum;
        candCount[n] = 0;                  // re-arm for next layer
        lossPartial[n] = (layer == 0) ? lsum : (lossPartial[n] + lsum);
        idxOut[(size_t)n * L_ + layer] = (float)k;
    }
}

// -------- FALLBACK distance GEMM + argmin (round-0 verbatim, proven) ------
#define FBM 128
#define FBN 128
#define FBKD 8
__global__ __launch_bounds__(256)
void rq_dist_argmin(const float* __restrict__ R, const float* __restrict__ E,
                    const float* __restrict__ rowNorm,
                    unsigned long long* __restrict__ keys)
{
    __shared__ float As[FBKD][FBM];
    __shared__ float Bs[FBKD][FBN];

    const int t  = threadIdx.x;
    const int tx = t & 15;
    const int ty = t >> 4;
    const int rowBase = blockIdx.y * FBM;
    const int colBase = blockIdx.x * FBN;

    const int lm   = t >> 1;
    const int lseg = (t & 1) * 4;

    const float* Aptr = R + (size_t)(rowBase + lm) * D_ + lseg;
    const float* Bptr = E + (size_t)(colBase + lm) * D_ + lseg;

    float acc[8][8];
#pragma unroll
    for (int i = 0; i < 8; ++i)
#pragma unroll
        for (int j = 0; j < 8; ++j) acc[i][j] = 0.0f;

    for (int dt = 0; dt < D_; dt += FBKD) {
        const float4 av = *(const float4*)(Aptr + dt);
        const float4 bv = *(const float4*)(Bptr + dt);
        __syncthreads();
        As[lseg + 0][lm] = av.x; As[lseg + 1][lm] = av.y;
        As[lseg + 2][lm] = av.z; As[lseg + 3][lm] = av.w;
        Bs[lseg + 0][lm] = bv.x; Bs[lseg + 1][lm] = bv.y;
        Bs[lseg + 2][lm] = bv.z; Bs[lseg + 3][lm] = bv.w;
        __syncthreads();
#pragma unroll
        for (int dd = 0; dd < FBKD; ++dd) {
            float a[8], b[8];
            *(float4*)&a[0] = *(const float4*)&As[dd][ty * 4];
            *(float4*)&a[4] = *(const float4*)&As[dd][ty * 4 + 64];
            *(float4*)&b[0] = *(const float4*)&Bs[dd][tx * 4];
            *(float4*)&b[4] = *(const float4*)&Bs[dd][tx * 4 + 64];
#pragma unroll
            for (int i = 0; i < 8; ++i)
#pragma unroll
                for (int j = 0; j < 8; ++j)
                    acc[i][j] = fmaf(a[i], b[j], acc[i][j]);
        }
    }

#pragma unroll
    for (int i = 0; i < 8; ++i) {
        const int rl = ty * 4 + (i & 3) + ((i >= 4) ? 64 : 0);
        const float An = rowNorm[rowBase + rl];
        unsigned long long best = 0xFFFFFFFFFFFFFFFFull;
#pragma unroll
        for (int j = 0; j < 8; ++j) {
            const int col = colBase + tx * 4 + (j & 3) + ((j >= 4) ? 64 : 0);
            const float c = __fsub_rn(An, 2.0f * acc[i][j]);
            const unsigned long long key =
                ((unsigned long long)__float_as_uint(c) << 32)
                | (unsigned int)col;
            if (key < best) best = key;
        }
#pragma unroll
        for (int m = 1; m < 16; m <<= 1) {
            const unsigned long long o = __shfl_xor(best, m, 64);
            if (o < best) best = o;
        }
        if (tx == 0)
            atomicMin(&keys[rowBase + rl], best);
    }
}

// -------- fallback per-layer update (keys-based, round-0 verbatim) --------
__global__ __launch_bounds__(256)
void rq_update(float* __restrict__ R, const float* __restrict__ E,
               unsigned long long* __restrict__ keys,
               float* __restrict__ qout, float* __restrict__ idxOut,
               float* __restrict__ rowNorm, double* __restrict__ lossPartial,
               int layer)
{
    const int wave = threadIdx.x >> 6;
    const int lane = threadIdx.x & 63;
    const int n = blockIdx.x * 4 + wave;
    const unsigned long long key = keys[n];
    const int k = (int)(key & 0xFFFFFFFFull);

    const float4* ep = (const float4*)(E + (size_t)k * D_);
    float4* rp = (float4*)(R + (size_t)n * D_);
    float4* qp = (float4*)(qout + (size_t)n * D_);

    double lsum = 0.0, asum = 0.0;
#pragma unroll
    for (int u = 0; u < 2; ++u) {
        const int idx = u * 64 + lane;
        float4 r4 = rp[idx];
        float4 q4 = ep[idx];
        float4 o4 = (layer == 0) ? make_float4(0.f, 0.f, 0.f, 0.f) : qp[idx];
        float rnew[4], qo[4];
        float rr[4] = {r4.x, r4.y, r4.z, r4.w};
        float qq[4] = {q4.x, q4.y, q4.z, q4.w};
        float oo[4] = {o4.x, o4.y, o4.z, o4.w};
#pragma unroll
        for (int c = 0; c < 4; ++c) {
            const float d1  = __fsub_rn(qq[c], rr[c]);
            const float qst = __fadd_rn(rr[c], d1);
            rnew[c] = __fsub_rn(rr[c], qst);
            qo[c]   = __fadd_rn(oo[c], qst);
            lsum += (double)d1 * (double)d1;
            asum += (double)rnew[c] * (double)rnew[c];
        }
        rp[idx] = make_float4(rnew[0], rnew[1], rnew[2], rnew[3]);
        qp[idx] = make_float4(qo[0], qo[1], qo[2], qo[3]);
    }
#pragma unroll
    for (int off = 32; off > 0; off >>= 1) {
        lsum += __shfl_down(lsum, off, 64);
        asum += __shfl_down(asum, off, 64);
    }
    if (lane == 0) {
        rowNorm[n] = (float)asum;
        keys[n] = 0xFFFFFFFFFFFFFFFFull;
        lossPartial[n] = (layer == 0) ? lsum : (lossPartial[n] + lsum);
        idxOut[(size_t)n * L_ + layer] = (float)k;
    }
}

// -------- finalize: sum 10496 per-row partials, scale ----------
__global__ __launch_bounds__(256)
void rq_finalize(float* __restrict__ lossOut,
                 const double* __restrict__ lossPartial)
{
    __shared__ double ws[4];
    const int t = threadIdx.x;
    double s = 0.0;
    for (int i = t; i < NROWS; i += 256) s += lossPartial[i];
#pragma unroll
    for (int off = 32; off > 0; off >>= 1)
        s += __shfl_down(s, off, 64);
    if ((t & 63) == 0) ws[t >> 6] = s;
    __syncthreads();
    if (t == 0) {
        double tot = ws[0] + ws[1] + ws[2] + ws[3];
        *lossOut = (float)(0.25 * tot / (double)QOUT_ELEMS);
    }
}

extern "C" void kernel_launch(void* const* d_in, const int* in_sizes, int n_in,
                              void* d_out, int out_size, void* d_ws, size_t ws_size,
                              hipStream_t stream)
{
    const float* x  = (const float*)d_in[0];
    const float* cb = (const float*)d_in[1];
    float* out = (float*)d_out;
    char* ws = (char*)d_ws;

    float* R = (float*)(ws + WS_R);
    float* rowNorm = (float*)(ws + WS_ROWNORM);
    unsigned long long* keys = (unsigned long long*)(ws + WS_KEYS);
    double* lossPartial = (double*)(ws + WS_LOSS);

    const bool fast = (ws_size >= (size_t)WS_NEEDED);
    f16* Rh = fast ? (f16*)(ws + WS_RH) : (f16*)nullptr;
    f16* Eh = fast ? (f16*)(ws + WS_EH) : (f16*)nullptr;
    int* candCount = fast ? (int*)(ws + WS_CCNT) : (int*)nullptr;
    float* bmax = fast ? (float*)(ws + WS_BMAX) : (float*)nullptr;
    unsigned long long* candList =
        fast ? (unsigned long long*)(ws + WS_CLIST) : (unsigned long long*)nullptr;

    float* idxOut = out + QOUT_ELEMS + 1;

    rq_init<<<NROWS / 4, 256, 0, stream>>>(x, R, rowNorm, keys, Rh, candCount);
    if (fast)
        rq_cvt_eh<<<(L_ * K_ * D_) / (4 * 256), 256, 0, stream>>>(cb, Eh);

    for (int l = 0; l < L_; ++l) {
        const float* E = cb + (size_t)l * K_ * D_;
        if (fast) {
            dim3 grid(K_ / 128, NROWS / 128);   // (32, 82)
            rq_screen_gemm<<<grid, 256, 0, stream>>>(
                Rh, Eh + (size_t)l * K_ * D_, rowNorm, candCount, candList,
                bmax);
            rq_select_update<<<NROWS / 4, 256, 0, stream>>>(
                candCount, candCount, candList, bmax, R, E, out, idxOut,
                rowNorm, lossPartial, l, Rh);
        } else {
            dim3 grid(K_ / FBN, NROWS / FBM);
            rq_dist_argmin<<<grid, 256, 0, stream>>>(R, E, rowNorm, keys);
            rq_update<<<NROWS / 4, 256, 0, stream>>>(R, E, keys, out, idxOut,
                                                     rowNorm, lossPartial, l);
        }
    }
    rq_finalize<<<1, 256, 0, stream>>>(out + QOUT_ELEMS, lossPartial);
}

// Round 8
// 2511.947 us; speedup vs baseline: 1.5661x; 1.0128x over previous
//
#include <hip/hip_runtime.h>
#include <cstdint>
#include <cstddef>

#define B_    256
#define W_    41
#define D_    512
#define K_    4096
#define L_    8
#define NROWS (B_ * W_)            // 10496
#define QOUT_ELEMS (NROWS * D_)    // 5373952

typedef _Float16 f16;
typedef __attribute__((ext_vector_type(4))) _Float16 f16x4;
typedef __attribute__((ext_vector_type(8))) _Float16 f16x8;
typedef __attribute__((ext_vector_type(4))) float f32x4;

// ---------------- workspace layout (bytes) ----------------
#define WS_R        0u            // 21,495,808
#define WS_ROWNORM  21495808u     //     41,984
#define WS_KEYS     21537792u     //     83,968
#define WS_LOSS     21621760u     //     83,968
#define WS_RH       21705728u     // 10,747,904
#define WS_EH       32453632u     // 33,554,432
#define WS_CCNT     66008064u     //     41,984
#define WS_BMAX     66050048u     //  1,343,488 (NROWS * 32 f32)
#define WS_CLIST    67393536u     // 21,495,808 (NROWS * CAP u64)
#define WS_NEEDED   88889344u

#define CAP 256

// async 16B global->LDS (gfx950). LDS dest must be WAVE-UNIFORM; HW writes
// dest + lane*16. Global src is per-lane. (guide §5 / m97 / m104)
__device__ __forceinline__ void gload_lds16(const void* g, void* l)
{
    __builtin_amdgcn_global_load_lds(
        (const __attribute__((address_space(1))) void*)g,
        (__attribute__((address_space(3))) void*)l, 16, 0, 0);
}

// -------- init: residual = x, rowNorm, arm keys + candidate counters ------
__global__ __launch_bounds__(256)
void rq_init(const float* __restrict__ x, float* __restrict__ R,
             float* __restrict__ rowNorm, unsigned long long* __restrict__ keys,
             f16* __restrict__ Rh, int* __restrict__ candCount)
{
    const int wave = threadIdx.x >> 6;
    const int lane = threadIdx.x & 63;
    const int n = blockIdx.x * 4 + wave;
    const float4* xp = (const float4*)(x + (size_t)n * D_);
    float4* rp = (float4*)(R + (size_t)n * D_);
    double asum = 0.0;
#pragma unroll
    for (int u = 0; u < 2; ++u) {
        const int idx = u * 64 + lane;
        float4 v = xp[idx];
        rp[idx] = v;
        if (Rh) {
            f16x4 hv; hv[0]=(_Float16)v.x; hv[1]=(_Float16)v.y;
            hv[2]=(_Float16)v.z; hv[3]=(_Float16)v.w;
            *(f16x4*)(Rh + (size_t)n * D_ + idx * 4) = hv;
        }
        asum += (double)v.x * v.x + (double)v.y * v.y
              + (double)v.z * v.z + (double)v.w * v.w;
    }
#pragma unroll
    for (int off = 32; off > 0; off >>= 1)
        asum += __shfl_down(asum, off, 64);
    if (lane == 0) {
        rowNorm[n] = (float)asum;
        keys[n] = 0xFFFFFFFFFFFFFFFFull;
        if (candCount) candCount[n] = 0;
    }
}

// -------- codebook fp32 -> f16 (all 8 layers, once) ----------
__global__ __launch_bounds__(256)
void rq_cvt_eh(const float* __restrict__ cb, f16* __restrict__ Eh)
{
    const size_t i = ((size_t)blockIdx.x * 256 + threadIdx.x) * 4;
    float4 v = *(const float4*)(cb + i);
    f16x4 h; h[0]=(_Float16)v.x; h[1]=(_Float16)v.y;
    h[2]=(_Float16)v.z; h[3]=(_Float16)v.w;
    *(f16x4*)(Eh + i) = h;
}

// -------- MFMA screen GEMM + fused candidate emission ----------
// S_acc[n][k] = Rh[n]·Eh[k] (f16 in, f32 acc), never stored densely.
// Round-8 change: K-loop staging ported to the m97 structure —
// global_load_lds width-16 direct-to-LDS (no VGPR round-trip, no ds_write),
// linear LDS [128 rows][64 B] (stride 16 dwords -> 2-row bank period ->
// conflict-free DMA writes AND ds_read_b128 fragment reads).
// Chunk map: c = wid*128 + i*64 + lane; LDS byte c*16 == row(c>>2)*64 +
// (c&3)*16 (consistent both sides, rule #21). MFMA operand VALUES are
// identical to round-7 -> screen output unchanged -> exactness preserved.
// Emission: per 128-col block, row max -> bmax[row][blk] AND every col with
// S_acc >= blockmax - tau appended as (bits(S)<<32|col). True winner always
// passes its own block's cut (chain spread + 2*e_f16 < tau); global filter +
// verbatim fp32-chain rescore in rq_select_update restores exactness.
__global__ __launch_bounds__(256)
void rq_screen_gemm(const f16* __restrict__ Rh, const f16* __restrict__ Eh,
                    const float* __restrict__ rowNorm,
                    int* __restrict__ candCount,
                    unsigned long long* __restrict__ candList,
                    float* __restrict__ bmax)
{
    __shared__ __align__(1024) char lds[16384];   // As [0,8K) | Bs [8K,16K)
    __shared__ float rmaxW[2][128];
    __shared__ float tauS[128];

    const int t    = threadIdx.x;
    const int lane = t & 63;
    const int wid  = t >> 6;
    const int wr   = (wid >> 1) * 64;     // wave quadrant row
    const int wc   = (wid & 1) * 64;      // wave quadrant col
    const int rowBase = blockIdx.y * 128;
    const int colBase = blockIdx.x * 128;

    const int r16 = lane & 15;
    const int ks  = lane >> 4;            // k-slot 0..3

    if (t < 128)
        tauS[t] = sqrtf(rowNorm[rowBase + t]) * 2.0e-5f + 3.0e-4f;

    // ---- staging geometry (wave-uniform LDS dest, per-lane global src) ----
    const int wu = __builtin_amdgcn_readfirstlane(wid);
    char* const As = lds;
    char* const Bs = lds + 8192;
    char* const lA = As + wu * 2048;      // issue0 at +0, issue1 at +1024
    char* const lB = Bs + wu * 2048;

    const int c0 = wu * 128 + lane;       // chunk index, issue 0
    const int r0 = c0 >> 2, k0 = (c0 & 3) * 8;
    const int c1 = c0 + 64;               // issue 1
    const int r1 = c1 >> 2, k1 = (c1 & 3) * 8;

    const f16* const gA0 = Rh + (size_t)(rowBase + r0) * D_ + k0;
    const f16* const gA1 = Rh + (size_t)(rowBase + r1) * D_ + k1;
    const f16* const gB0 = Eh + (size_t)(colBase + r0) * D_ + k0;
    const f16* const gB1 = Eh + (size_t)(colBase + r1) * D_ + k1;

    f32x4 acc[4][4];
#pragma unroll
    for (int i = 0; i < 4; ++i)
#pragma unroll
        for (int j = 0; j < 4; ++j) acc[i][j] = (f32x4){0.f, 0.f, 0.f, 0.f};

    for (int dt = 0; dt < D_; dt += 32) {
        __syncthreads();                  // prev iter's ds_reads complete
        gload_lds16(gA0 + dt, lA);
        gload_lds16(gA1 + dt, lA + 1024);
        gload_lds16(gB0 + dt, lB);
        gload_lds16(gB1 + dt, lB + 1024);
        __syncthreads();                  // vmcnt(0) drain -> tile ready

        f16x8 af[4], bf[4];
#pragma unroll
        for (int mi = 0; mi < 4; ++mi)
            af[mi] = *(const f16x8*)(As + (wr + mi * 16 + r16) * 64 + ks * 16);
#pragma unroll
        for (int ni = 0; ni < 4; ++ni)
            bf[ni] = *(const f16x8*)(Bs + (wc + ni * 16 + r16) * 64 + ks * 16);
#pragma unroll
        for (int mi = 0; mi < 4; ++mi)
#pragma unroll
            for (int ni = 0; ni < 4; ++ni)
                acc[mi][ni] = __builtin_amdgcn_mfma_f32_16x16x32_f16(
                    af[mi], bf[ni], acc[mi][ni], 0, 0, 0);
    }

    // ---- epilogue: per-row block max + candidate emission ----
    // C/D layout (m89): reg i of lane l -> row (l>>4)*4+i, col l&15
    const int g = lane >> 4;

    float vmax[4][4];
#pragma unroll
    for (int mi = 0; mi < 4; ++mi)
#pragma unroll
        for (int i = 0; i < 4; ++i) {
            float m0 = fmaxf(acc[mi][0][i], acc[mi][1][i]);
            float m1 = fmaxf(acc[mi][2][i], acc[mi][3][i]);
            vmax[mi][i] = fmaxf(m0, m1);
        }
#pragma unroll
    for (int off = 1; off < 16; off <<= 1)
#pragma unroll
        for (int mi = 0; mi < 4; ++mi)
#pragma unroll
            for (int i = 0; i < 4; ++i)
                vmax[mi][i] = fmaxf(vmax[mi][i],
                                    __shfl_xor(vmax[mi][i], off, 64));
    if (r16 == 0) {
#pragma unroll
        for (int mi = 0; mi < 4; ++mi)
#pragma unroll
            for (int i = 0; i < 4; ++i)
                rmaxW[wid & 1][wr + mi * 16 + g * 4 + i] = vmax[mi][i];
    }
    __syncthreads();

    if (t < 128)   // publish per-block row max for the global filter
        bmax[(size_t)(rowBase + t) * 32 + blockIdx.x]
            = fmaxf(rmaxW[0][t], rmaxW[1][t]);

#pragma unroll
    for (int mi = 0; mi < 4; ++mi)
#pragma unroll
        for (int i = 0; i < 4; ++i) {
            const int lrow = wr + mi * 16 + g * 4 + i;
            const float thr = fmaxf(rmaxW[0][lrow], rmaxW[1][lrow])
                              - tauS[lrow];
            const int grow = rowBase + lrow;
#pragma unroll
            for (int ni = 0; ni < 4; ++ni) {
                const float sv = acc[mi][ni][i];
                if (sv >= thr) {
                    const int pos = atomicAdd(&candCount[grow], 1);
                    if (pos < CAP)
                        candList[(size_t)grow * CAP + pos] =
                            ((unsigned long long)__float_as_uint(sv) << 32)
                            | (unsigned int)(colBase + wc + ni * 16 + r16);
                }
            }
        }
}

// -------- exact rescore helper: verbatim ascending-d fp32 fmaf chain ------
__device__ __forceinline__ unsigned long long
rescore_key(const float4* __restrict__ a4, const float* __restrict__ E,
            int col, float An)
{
    const float4* b4 = (const float4*)(E + (size_t)col * D_);
    float acc = 0.f;
    for (int d = 0; d < 128; ++d) {
        const float4 a = a4[d], b = b4[d];
        acc = fmaf(a.x, b.x, acc); acc = fmaf(a.y, b.y, acc);
        acc = fmaf(a.z, b.z, acc); acc = fmaf(a.w, b.w, acc);
    }
    const float c = __fsub_rn(An, 2.0f * acc);
    return ((unsigned long long)__float_as_uint(c) << 32) | (unsigned int)col;
}

// -------- fused select + STE update: one wave per row ----------
// (1) gmax = max over the row's 32 per-block maxes; global filter
//     S >= gmax - tau keeps the true winner (same bound as screen's cut).
// (2) exact rescore of the ~2-6 survivors (verbatim fp32 chain);
//     u64 (c,k) min == np.argmin first-index tie rule.
// (3) STE epilogue identical to the proven rq_update (R row cache-hot).
__global__ __launch_bounds__(256)
void rq_select_update(const int* __restrict__ candCountIn,
                      int* __restrict__ candCount,
                      const unsigned long long* __restrict__ candList,
                      const float* __restrict__ bmax,
                      float* __restrict__ R, const float* __restrict__ E,
                      float* __restrict__ qout, float* __restrict__ idxOut,
                      float* __restrict__ rowNorm,
                      double* __restrict__ lossPartial,
                      int layer, f16* __restrict__ Rh)
{
    const int lane = threadIdx.x & 63;
    const int wv   = threadIdx.x >> 6;
    const int n    = blockIdx.x * 4 + wv;
    const float An = rowNorm[n];
    const float4* a4 = (const float4*)(R + (size_t)n * D_);

    // global row max from the 32 per-block maxes
    float gm = bmax[(size_t)n * 32 + (lane & 31)];
#pragma unroll
    for (int off = 1; off < 32; off <<= 1)
        gm = fmaxf(gm, __shfl_xor(gm, off, 64));
    const float tau = sqrtf(An) * 2.0e-5f + 3.0e-4f;
    const float thr = gm - tau;

    unsigned long long best = 0xFFFFFFFFFFFFFFFFull;
    const int cnt = candCountIn[n];

    if (cnt <= CAP) {
        const unsigned long long* cl = candList + (size_t)n * CAP;
        for (int base = 0; base < cnt; base += 64) {
            const int ci = base + lane;
            if (ci < cnt) {
                const unsigned long long e = cl[ci];
                const float sv = __uint_as_float((unsigned int)(e >> 32));
                if (sv >= thr) {
                    const int col = (int)(e & 0xFFFFFFFFull);
                    const unsigned long long k = rescore_key(a4, E, col, An);
                    if (k < best) best = k;
                }
            }
        }
    } else {
        // correctness-safe fallback: exact scan of all K cols
        for (int col = lane; col < K_; col += 64) {
            const unsigned long long k = rescore_key(a4, E, col, An);
            if (k < best) best = k;
        }
    }
#pragma unroll
    for (int mm = 1; mm < 64; mm <<= 1) {
        const unsigned long long o = __shfl_xor(best, mm, 64);
        if (o < best) best = o;
    }
    const int k = (int)(best & 0xFFFFFFFFull);

    // ---- STE update (verbatim exact fp32 replication) ----
    const float4* ep = (const float4*)(E + (size_t)k * D_);
    float4* rp = (float4*)(R + (size_t)n * D_);
    float4* qp = (float4*)(qout + (size_t)n * D_);

    double lsum = 0.0, asum = 0.0;
#pragma unroll
    for (int u = 0; u < 2; ++u) {
        const int idx = u * 64 + lane;
        float4 r4 = rp[idx];
        float4 q4 = ep[idx];
        float4 o4 = (layer == 0) ? make_float4(0.f, 0.f, 0.f, 0.f) : qp[idx];
        float rnew[4], qo[4];
        float rr[4] = {r4.x, r4.y, r4.z, r4.w};
        float qq[4] = {q4.x, q4.y, q4.z, q4.w};
        float oo[4] = {o4.x, o4.y, o4.z, o4.w};
#pragma unroll
        for (int c = 0; c < 4; ++c) {
            const float d1  = __fsub_rn(qq[c], rr[c]);
            const float qst = __fadd_rn(rr[c], d1);
            rnew[c] = __fsub_rn(rr[c], qst);
            qo[c]   = __fadd_rn(oo[c], qst);
            lsum += (double)d1 * (double)d1;
            asum += (double)rnew[c] * (double)rnew[c];
        }
        rp[idx] = make_float4(rnew[0], rnew[1], rnew[2], rnew[3]);
        qp[idx] = make_float4(qo[0], qo[1], qo[2], qo[3]);
        if (layer < L_ - 1) {
            f16x4 hv; hv[0]=(_Float16)rnew[0]; hv[1]=(_Float16)rnew[1];
            hv[2]=(_Float16)rnew[2]; hv[3]=(_Float16)rnew[3];
            *(f16x4*)(Rh + (size_t)n * D_ + idx * 4) = hv;
        }
    }
#pragma unroll
    for (int off = 32; off > 0; off >>= 1) {
        lsum += __shfl_down(lsum, off, 64);
        asum += __shfl_down(asum, off, 64);
    }
    if (lane == 0) {
        rowNorm[n] = (float)asum;
        candCount[n] = 0;                  // re-arm for next layer
        lossPartial[n] = (layer == 0) ? lsum : (lossPartial[n] + lsum);
        idxOut[(size_t)n * L_ + layer] = (float)k;
    }
}

// -------- FALLBACK distance GEMM + argmin (round-0 verbatim, proven) ------
#define FBM 128
#define FBN 128
#define FBKD 8
__global__ __launch_bounds__(256)
void rq_dist_argmin(const float* __restrict__ R, const float* __restrict__ E,
                    const float* __restrict__ rowNorm,
                    unsigned long long* __restrict__ keys)
{
    __shared__ float As[FBKD][FBM];
    __shared__ float Bs[FBKD][FBN];

    const int t  = threadIdx.x;
    const int tx = t & 15;
    const int ty = t >> 4;
    const int rowBase = blockIdx.y * FBM;
    const int colBase = blockIdx.x * FBN;

    const int lm   = t >> 1;
    const int lseg = (t & 1) * 4;

    const float* Aptr = R + (size_t)(rowBase + lm) * D_ + lseg;
    const float* Bptr = E + (size_t)(colBase + lm) * D_ + lseg;

    float acc[8][8];
#pragma unroll
    for (int i = 0; i < 8; ++i)
#pragma unroll
        for (int j = 0; j < 8; ++j) acc[i][j] = 0.0f;

    for (int dt = 0; dt < D_; dt += FBKD) {
        const float4 av = *(const float4*)(Aptr + dt);
        const float4 bv = *(const float4*)(Bptr + dt);
        __syncthreads();
        As[lseg + 0][lm] = av.x; As[lseg + 1][lm] = av.y;
        As[lseg + 2][lm] = av.z; As[lseg + 3][lm] = av.w;
        Bs[lseg + 0][lm] = bv.x; Bs[lseg + 1][lm] = bv.y;
        Bs[lseg + 2][lm] = bv.z; Bs[lseg + 3][lm] = bv.w;
        __syncthreads();
#pragma unroll
        for (int dd = 0; dd < FBKD; ++dd) {
            float a[8], b[8];
            *(float4*)&a[0] = *(const float4*)&As[dd][ty * 4];
            *(float4*)&a[4] = *(const float4*)&As[dd][ty * 4 + 64];
            *(float4*)&b[0] = *(const float4*)&Bs[dd][tx * 4];
            *(float4*)&b[4] = *(const float4*)&Bs[dd][tx * 4 + 64];
#pragma unroll
            for (int i = 0; i < 8; ++i)
#pragma unroll
                for (int j = 0; j < 8; ++j)
                    acc[i][j] = fmaf(a[i], b[j], acc[i][j]);
        }
    }

#pragma unroll
    for (int i = 0; i < 8; ++i) {
        const int rl = ty * 4 + (i & 3) + ((i >= 4) ? 64 : 0);
        const float An = rowNorm[rowBase + rl];
        unsigned long long best = 0xFFFFFFFFFFFFFFFFull;
#pragma unroll
        for (int j = 0; j < 8; ++j) {
            const int col = colBase + tx * 4 + (j & 3) + ((j >= 4) ? 64 : 0);
            const float c = __fsub_rn(An, 2.0f * acc[i][j]);
            const unsigned long long key =
                ((unsigned long long)__float_as_uint(c) << 32)
                | (unsigned int)col;
            if (key < best) best = key;
        }
#pragma unroll
        for (int m = 1; m < 16; m <<= 1) {
            const unsigned long long o = __shfl_xor(best, m, 64);
            if (o < best) best = o;
        }
        if (tx == 0)
            atomicMin(&keys[rowBase + rl], best);
    }
}

// -------- fallback per-layer update (keys-based, round-0 verbatim) --------
__global__ __launch_bounds__(256)
void rq_update(float* __restrict__ R, const float* __restrict__ E,
               unsigned long long* __restrict__ keys,
               float* __restrict__ qout, float* __restrict__ idxOut,
               float* __restrict__ rowNorm, double* __restrict__ lossPartial,
               int layer)
{
    const int wave = threadIdx.x >> 6;
    const int lane = threadIdx.x & 63;
    const int n = blockIdx.x * 4 + wave;
    const unsigned long long key = keys[n];
    const int k = (int)(key & 0xFFFFFFFFull);

    const float4* ep = (const float4*)(E + (size_t)k * D_);
    float4* rp = (float4*)(R + (size_t)n * D_);
    float4* qp = (float4*)(qout + (size_t)n * D_);

    double lsum = 0.0, asum = 0.0;
#pragma unroll
    for (int u = 0; u < 2; ++u) {
        const int idx = u * 64 + lane;
        float4 r4 = rp[idx];
        float4 q4 = ep[idx];
        float4 o4 = (layer == 0) ? make_float4(0.f, 0.f, 0.f, 0.f) : qp[idx];
        float rnew[4], qo[4];
        float rr[4] = {r4.x, r4.y, r4.z, r4.w};
        float qq[4] = {q4.x, q4.y, q4.z, q4.w};
        float oo[4] = {o4.x, o4.y, o4.z, o4.w};
#pragma unroll
        for (int c = 0; c < 4; ++c) {
            const float d1  = __fsub_rn(qq[c], rr[c]);
            const float qst = __fadd_rn(rr[c], d1);
            rnew[c] = __fsub_rn(rr[c], qst);
            qo[c]   = __fadd_rn(oo[c], qst);
            lsum += (double)d1 * (double)d1;
            asum += (double)rnew[c] * (double)rnew[c];
        }
        rp[idx] = make_float4(rnew[0], rnew[1], rnew[2], rnew[3]);
        qp[idx] = make_float4(qo[0], qo[1], qo[2], qo[3]);
    }
#pragma unroll
    for (int off = 32; off > 0; off >>= 1) {
        lsum += __shfl_down(lsum, off, 64);
        asum += __shfl_down(asum, off, 64);
    }
    if (lane == 0) {
        rowNorm[n] = (float)asum;
        keys[n] = 0xFFFFFFFFFFFFFFFFull;
        lossPartial[n] = (layer == 0) ? lsum : (lossPartial[n] + lsum);
        idxOut[(size_t)n * L_ + layer] = (float)k;
    }
}

// -------- finalize: sum 10496 per-row partials, scale ----------
__global__ __launch_bounds__(256)
void rq_finalize(float* __restrict__ lossOut,
                 const double* __restrict__ lossPartial)
{
    __shared__ double ws[4];
    const int t = threadIdx.x;
    double s = 0.0;
    for (int i = t; i < NROWS; i += 256) s += lossPartial[i];
#pragma unroll
    for (int off = 32; off > 0; off >>= 1)
        s += __shfl_down(s, off, 64);
    if ((t & 63) == 0) ws[t >> 6] = s;
    __syncthreads();
    if (t == 0) {
        double tot = ws[0] + ws[1] + ws[2] + ws[3];
        *lossOut = (float)(0.25 * tot / (double)QOUT_ELEMS);
    }
}

extern "C" void kernel_launch(void* const* d_in, const int* in_sizes, int n_in,
                              void* d_out, int out_size, void* d_ws, size_t ws_size,
                              hipStream_t stream)
{
    const float* x  = (const float*)d_in[0];
    const float* cb = (const float*)d_in[1];
    float* out = (float*)d_out;
    char* ws = (char*)d_ws;

    float* R = (float*)(ws + WS_R);
    float* rowNorm = (float*)(ws + WS_ROWNORM);
    unsigned long long* keys = (unsigned long long*)(ws + WS_KEYS);
    double* lossPartial = (double*)(ws + WS_LOSS);

    const bool fast = (ws_size >= (size_t)WS_NEEDED);
    f16* Rh = fast ? (f16*)(ws + WS_RH) : (f16*)nullptr;
    f16* Eh = fast ? (f16*)(ws + WS_EH) : (f16*)nullptr;
    int* candCount = fast ? (int*)(ws + WS_CCNT) : (int*)nullptr;
    float* bmax = fast ? (float*)(ws + WS_BMAX) : (float*)nullptr;
    unsigned long long* candList =
        fast ? (unsigned long long*)(ws + WS_CLIST) : (unsigned long long*)nullptr;

    float* idxOut = out + QOUT_ELEMS + 1;

    rq_init<<<NROWS / 4, 256, 0, stream>>>(x, R, rowNorm, keys, Rh, candCount);
    if (fast)
        rq_cvt_eh<<<(L_ * K_ * D_) / (4 * 256), 256, 0, stream>>>(cb, Eh);

    for (int l = 0; l < L_; ++l) {
        const float* E = cb + (size_t)l * K_ * D_;
        if (fast) {
            dim3 grid(K_ / 128, NROWS / 128);   // (32, 82)
            rq_screen_gemm<<<grid, 256, 0, stream>>>(
                Rh, Eh + (size_t)l * K_ * D_, rowNorm, candCount, candList,
                bmax);
            rq_select_update<<<NROWS / 4, 256, 0, stream>>>(
                candCount, candCount, candList, bmax, R, E, out, idxOut,
                rowNorm, lossPartial, l, Rh);
        } else {
            dim3 grid(K_ / FBN, NROWS / FBM);
            rq_dist_argmin<<<grid, 256, 0, stream>>>(R, E, rowNorm, keys);
            rq_update<<<NROWS / 4, 256, 0, stream>>>(R, E, keys, out, idxOut,
                                                     rowNorm, lossPartial, l);
        }
    }
    rq_finalize<<<1, 256, 0, stream>>>(out + QOUT_ELEMS, lossPartial);
}

// Round 9
// 2463.650 us; speedup vs baseline: 1.5968x; 1.0196x over previous
//
#include <hip/hip_runtime.h>
#include <cstdint>
#include <cstddef>

#define B_    256
#define W_    41
#define D_    512
#define K_    4096
#define L_    8
#define NROWS (B_ * W_)            // 10496
#define QOUT_ELEMS (NROWS * D_)    // 5373952

typedef _Float16 f16;
typedef __attribute__((ext_vector_type(4))) _Float16 f16x4;
typedef __attribute__((ext_vector_type(8))) _Float16 f16x8;
typedef __attribute__((ext_vector_type(4))) float f32x4;

// ---------------- workspace layout (bytes) ----------------
#define WS_R        0u            // 21,495,808
#define WS_ROWNORM  21495808u     //     41,984
#define WS_KEYS     21537792u     //     83,968
#define WS_LOSS     21621760u     //     83,968
#define WS_RH       21705728u     // 10,747,904
#define WS_EH       32453632u     // 33,554,432
#define WS_CCNT     66008064u     //     41,984
#define WS_BMAX     66050048u     //  1,343,488 (NROWS * 32 f32)
#define WS_CLIST    67393536u     // 21,495,808 (NROWS * CAP u64)
#define WS_NEEDED   88889344u

#define CAP 256

// async 16B global->LDS (gfx950). LDS dest must be WAVE-UNIFORM; HW writes
// dest + lane*16. Global src is per-lane. (guide §5 / m97 / m104)
__device__ __forceinline__ void gload_lds16(const void* g, void* l)
{
    __builtin_amdgcn_global_load_lds(
        (const __attribute__((address_space(1))) void*)g,
        (__attribute__((address_space(3))) void*)l, 16, 0, 0);
}

// -------- init: residual = x, rowNorm, arm keys + candidate counters ------
__global__ __launch_bounds__(256)
void rq_init(const float* __restrict__ x, float* __restrict__ R,
             float* __restrict__ rowNorm, unsigned long long* __restrict__ keys,
             f16* __restrict__ Rh, int* __restrict__ candCount)
{
    const int wave = threadIdx.x >> 6;
    const int lane = threadIdx.x & 63;
    const int n = blockIdx.x * 4 + wave;
    const float4* xp = (const float4*)(x + (size_t)n * D_);
    float4* rp = (float4*)(R + (size_t)n * D_);
    double asum = 0.0;
#pragma unroll
    for (int u = 0; u < 2; ++u) {
        const int idx = u * 64 + lane;
        float4 v = xp[idx];
        rp[idx] = v;
        if (Rh) {
            f16x4 hv; hv[0]=(_Float16)v.x; hv[1]=(_Float16)v.y;
            hv[2]=(_Float16)v.z; hv[3]=(_Float16)v.w;
            *(f16x4*)(Rh + (size_t)n * D_ + idx * 4) = hv;
        }
        asum += (double)v.x * v.x + (double)v.y * v.y
              + (double)v.z * v.z + (double)v.w * v.w;
    }
#pragma unroll
    for (int off = 32; off > 0; off >>= 1)
        asum += __shfl_down(asum, off, 64);
    if (lane == 0) {
        rowNorm[n] = (float)asum;
        keys[n] = 0xFFFFFFFFFFFFFFFFull;
        if (candCount) candCount[n] = 0;
    }
}

// -------- codebook fp32 -> f16 (all 8 layers, once) ----------
__global__ __launch_bounds__(256)
void rq_cvt_eh(const float* __restrict__ cb, f16* __restrict__ Eh)
{
    const size_t i = ((size_t)blockIdx.x * 256 + threadIdx.x) * 4;
    float4 v = *(const float4*)(cb + i);
    f16x4 h; h[0]=(_Float16)v.x; h[1]=(_Float16)v.y;
    h[2]=(_Float16)v.z; h[3]=(_Float16)v.w;
    *(f16x4*)(Eh + i) = h;
}

// -------- MFMA screen GEMM + fused candidate emission ----------
// Round-9 change: DOUBLE-BUFFERED LDS, prefetch-next-tile, ONE barrier per
// K-step (T3 minimal 2-phase). Round-8 post-mortem: single-buffered
// 2-barrier loop exposed the full global-load latency (~200-900 cyc) every
// K-iter against ~150 cyc of compute (MfmaUtil 8%, VALUBusy 9% — everything
// idle = latency-bound). Now tile t+1's 4 gload_lds are issued BEFORE tile
// t's ds_read+MFMA; the single __syncthreads (implicit vmcnt(0)+lgkmcnt(0)
// drain) lands after the compute, hiding most of the load latency. Buffer
// written at iter t was last read at iter t-1 and drained by that barrier ->
// single barrier/iter is race-free. MFMA operand VALUES identical to r7/r8
// (same chunk map) -> screen output unchanged -> exactness preserved.
// Emission: per 128-col block, row max -> bmax[row][blk] AND every col with
// S_acc >= blockmax - tau appended as (bits(S)<<32|col). True winner always
// passes its own block's cut (chain spread + 2*e_f16 < tau); global filter +
// verbatim fp32-chain rescore in rq_select_update restores exactness.
__global__ __launch_bounds__(256)
void rq_screen_gemm(const f16* __restrict__ Rh, const f16* __restrict__ Eh,
                    const float* __restrict__ rowNorm,
                    int* __restrict__ candCount,
                    unsigned long long* __restrict__ candList,
                    float* __restrict__ bmax)
{
    // buffer b at lds + b*16384: A [0,8K), B [8K,16K)
    __shared__ __align__(1024) char lds[32768];
    __shared__ float rmaxW[2][128];
    __shared__ float tauS[128];

    const int t    = threadIdx.x;
    const int lane = t & 63;
    const int wid  = t >> 6;
    const int wr   = (wid >> 1) * 64;     // wave quadrant row
    const int wc   = (wid & 1) * 64;      // wave quadrant col
    const int rowBase = blockIdx.y * 128;
    const int colBase = blockIdx.x * 128;

    const int r16 = lane & 15;
    const int ks  = lane >> 4;            // k-slot 0..3

    if (t < 128)
        tauS[t] = sqrtf(rowNorm[rowBase + t]) * 2.0e-5f + 3.0e-4f;

    // ---- staging geometry (wave-uniform LDS dest, per-lane global src) ----
    // chunk c = wid*128 + i*64 + lane; LDS byte c*16 == row(c>>2)*64 +
    // (c&3)*16 (consistent both sides, rule #21).
    const int wu = __builtin_amdgcn_readfirstlane(wid);

    const int c0 = wu * 128 + lane;       // chunk index, issue 0
    const int r0 = c0 >> 2, k0 = (c0 & 3) * 8;
    const int c1 = c0 + 64;               // issue 1
    const int r1 = c1 >> 2, k1 = (c1 & 3) * 8;

    const f16* const gA0 = Rh + (size_t)(rowBase + r0) * D_ + k0;
    const f16* const gA1 = Rh + (size_t)(rowBase + r1) * D_ + k1;
    const f16* const gB0 = Eh + (size_t)(colBase + r0) * D_ + k0;
    const f16* const gB1 = Eh + (size_t)(colBase + r1) * D_ + k1;

    f32x4 acc[4][4];
#pragma unroll
    for (int i = 0; i < 4; ++i)
#pragma unroll
        for (int j = 0; j < 4; ++j) acc[i][j] = (f32x4){0.f, 0.f, 0.f, 0.f};

    // prologue: stage tile 0 into buffer 0
    {
        char* const b = lds;
        gload_lds16(gA0, b + wu * 2048);
        gload_lds16(gA1, b + wu * 2048 + 1024);
        gload_lds16(gB0, b + 8192 + wu * 2048);
        gload_lds16(gB1, b + 8192 + wu * 2048 + 1024);
    }
    __syncthreads();                      // vmcnt(0) drain -> tile 0 ready

    char* cur = lds;
    char* nxt = lds + 16384;

    for (int dt = 0; dt < D_; dt += 32) {
        // issue next tile's loads first (hidden under this tile's compute)
        if (dt + 32 < D_) {
            gload_lds16(gA0 + dt + 32, nxt + wu * 2048);
            gload_lds16(gA1 + dt + 32, nxt + wu * 2048 + 1024);
            gload_lds16(gB0 + dt + 32, nxt + 8192 + wu * 2048);
            gload_lds16(gB1 + dt + 32, nxt + 8192 + wu * 2048 + 1024);
        }

        f16x8 af[4], bf[4];
#pragma unroll
        for (int mi = 0; mi < 4; ++mi)
            af[mi] = *(const f16x8*)(cur + (wr + mi * 16 + r16) * 64 + ks * 16);
#pragma unroll
        for (int ni = 0; ni < 4; ++ni)
            bf[ni] = *(const f16x8*)(cur + 8192 + (wc + ni * 16 + r16) * 64 + ks * 16);
#pragma unroll
        for (int mi = 0; mi < 4; ++mi)
#pragma unroll
            for (int ni = 0; ni < 4; ++ni)
                acc[mi][ni] = __builtin_amdgcn_mfma_f32_16x16x32_f16(
                    af[mi], bf[ni], acc[mi][ni], 0, 0, 0);

        __syncthreads();   // drains next-tile loads AND this tile's ds_reads
        char* tmp = cur; cur = nxt; nxt = tmp;
    }

    // ---- epilogue: per-row block max + candidate emission ----
    // C/D layout (m89): reg i of lane l -> row (l>>4)*4+i, col l&15
    const int g = lane >> 4;

    float vmax[4][4];
#pragma unroll
    for (int mi = 0; mi < 4; ++mi)
#pragma unroll
        for (int i = 0; i < 4; ++i) {
            float m0 = fmaxf(acc[mi][0][i], acc[mi][1][i]);
            float m1 = fmaxf(acc[mi][2][i], acc[mi][3][i]);
            vmax[mi][i] = fmaxf(m0, m1);
        }
#pragma unroll
    for (int off = 1; off < 16; off <<= 1)
#pragma unroll
        for (int mi = 0; mi < 4; ++mi)
#pragma unroll
            for (int i = 0; i < 4; ++i)
                vmax[mi][i] = fmaxf(vmax[mi][i],
                                    __shfl_xor(vmax[mi][i], off, 64));
    if (r16 == 0) {
#pragma unroll
        for (int mi = 0; mi < 4; ++mi)
#pragma unroll
            for (int i = 0; i < 4; ++i)
                rmaxW[wid & 1][wr + mi * 16 + g * 4 + i] = vmax[mi][i];
    }
    __syncthreads();

    if (t < 128)   // publish per-block row max for the global filter
        bmax[(size_t)(rowBase + t) * 32 + blockIdx.x]
            = fmaxf(rmaxW[0][t], rmaxW[1][t]);

#pragma unroll
    for (int mi = 0; mi < 4; ++mi)
#pragma unroll
        for (int i = 0; i < 4; ++i) {
            const int lrow = wr + mi * 16 + g * 4 + i;
            const float thr = fmaxf(rmaxW[0][lrow], rmaxW[1][lrow])
                              - tauS[lrow];
            const int grow = rowBase + lrow;
#pragma unroll
            for (int ni = 0; ni < 4; ++ni) {
                const float sv = acc[mi][ni][i];
                if (sv >= thr) {
                    const int pos = atomicAdd(&candCount[grow], 1);
                    if (pos < CAP)
                        candList[(size_t)grow * CAP + pos] =
                            ((unsigned long long)__float_as_uint(sv) << 32)
                            | (unsigned int)(colBase + wc + ni * 16 + r16);
                }
            }
        }
}

// -------- exact rescore helper: verbatim ascending-d fp32 fmaf chain ------
__device__ __forceinline__ unsigned long long
rescore_key(const float4* __restrict__ a4, const float* __restrict__ E,
            int col, float An)
{
    const float4* b4 = (const float4*)(E + (size_t)col * D_);
    float acc = 0.f;
    for (int d = 0; d < 128; ++d) {
        const float4 a = a4[d], b = b4[d];
        acc = fmaf(a.x, b.x, acc); acc = fmaf(a.y, b.y, acc);
        acc = fmaf(a.z, b.z, acc); acc = fmaf(a.w, b.w, acc);
    }
    const float c = __fsub_rn(An, 2.0f * acc);
    return ((unsigned long long)__float_as_uint(c) << 32) | (unsigned int)col;
}

// -------- fused select + STE update: one wave per row ----------
// (1) gmax = max over the row's 32 per-block maxes; global filter
//     S >= gmax - tau keeps the true winner (same bound as screen's cut).
// (2) exact rescore of the ~2-6 survivors (verbatim fp32 chain);
//     u64 (c,k) min == np.argmin first-index tie rule.
// (3) STE epilogue identical to the proven rq_update (R row cache-hot).
__global__ __launch_bounds__(256)
void rq_select_update(const int* __restrict__ candCountIn,
                      int* __restrict__ candCount,
                      const unsigned long long* __restrict__ candList,
                      const float* __restrict__ bmax,
                      float* __restrict__ R, const float* __restrict__ E,
                      float* __restrict__ qout, float* __restrict__ idxOut,
                      float* __restrict__ rowNorm,
                      double* __restrict__ lossPartial,
                      int layer, f16* __restrict__ Rh)
{
    const int lane = threadIdx.x & 63;
    const int wv   = threadIdx.x >> 6;
    const int n    = blockIdx.x * 4 + wv;
    const float An = rowNorm[n];
    const float4* a4 = (const float4*)(R + (size_t)n * D_);

    // global row max from the 32 per-block maxes
    float gm = bmax[(size_t)n * 32 + (lane & 31)];
#pragma unroll
    for (int off = 1; off < 32; off <<= 1)
        gm = fmaxf(gm, __shfl_xor(gm, off, 64));
    const float tau = sqrtf(An) * 2.0e-5f + 3.0e-4f;
    const float thr = gm - tau;

    unsigned long long best = 0xFFFFFFFFFFFFFFFFull;
    const int cnt = candCountIn[n];

    if (cnt <= CAP) {
        const unsigned long long* cl = candList + (size_t)n * CAP;
        for (int base = 0; base < cnt; base += 64) {
            const int ci = base + lane;
            if (ci < cnt) {
                const unsigned long long e = cl[ci];
                const float sv = __uint_as_float((unsigned int)(e >> 32));
                if (sv >= thr) {
                    const int col = (int)(e & 0xFFFFFFFFull);
                    const unsigned long long k = rescore_key(a4, E, col, An);
                    if (k < best) best = k;
                }
            }
        }
    } else {
        // correctness-safe fallback: exact scan of all K cols
        for (int col = lane; col < K_; col += 64) {
            const unsigned long long k = rescore_key(a4, E, col, An);
            if (k < best) best = k;
        }
    }
#pragma unroll
    for (int mm = 1; mm < 64; mm <<= 1) {
        const unsigned long long o = __shfl_xor(best, mm, 64);
        if (o < best) best = o;
    }
    const int k = (int)(best & 0xFFFFFFFFull);

    // ---- STE update (verbatim exact fp32 replication) ----
    const float4* ep = (const float4*)(E + (size_t)k * D_);
    float4* rp = (float4*)(R + (size_t)n * D_);
    float4* qp = (float4*)(qout + (size_t)n * D_);

    double lsum = 0.0, asum = 0.0;
#pragma unroll
    for (int u = 0; u < 2; ++u) {
        const int idx = u * 64 + lane;
        float4 r4 = rp[idx];
        float4 q4 = ep[idx];
        float4 o4 = (layer == 0) ? make_float4(0.f, 0.f, 0.f, 0.f) : qp[idx];
        float rnew[4], qo[4];
        float rr[4] = {r4.x, r4.y, r4.z, r4.w};
        float qq[4] = {q4.x, q4.y, q4.z, q4.w};
        float oo[4] = {o4.x, o4.y, o4.z, o4.w};
#pragma unroll
        for (int c = 0; c < 4; ++c) {
            const float d1  = __fsub_rn(qq[c], rr[c]);
            const float qst = __fadd_rn(rr[c], d1);
            rnew[c] = __fsub_rn(rr[c], qst);
            qo[c]   = __fadd_rn(oo[c], qst);
            lsum += (double)d1 * (double)d1;
            asum += (double)rnew[c] * (double)rnew[c];
        }
        rp[idx] = make_float4(rnew[0], rnew[1], rnew[2], rnew[3]);
        qp[idx] = make_float4(qo[0], qo[1], qo[2], qo[3]);
        if (layer < L_ - 1) {
            f16x4 hv; hv[0]=(_Float16)rnew[0]; hv[1]=(_Float16)rnew[1];
            hv[2]=(_Float16)rnew[2]; hv[3]=(_Float16)rnew[3];
            *(f16x4*)(Rh + (size_t)n * D_ + idx * 4) = hv;
        }
    }
#pragma unroll
    for (int off = 32; off > 0; off >>= 1) {
        lsum += __shfl_down(lsum, off, 64);
        asum += __shfl_down(asum, off, 64);
    }
    if (lane == 0) {
        rowNorm[n] = (float)asum;
        candCount[n] = 0;                  // re-arm for next layer
        lossPartial[n] = (layer == 0) ? lsum : (lossPartial[n] + lsum);
        idxOut[(size_t)n * L_ + layer] = (float)k;
    }
}

// -------- FALLBACK distance GEMM + argmin (round-0 verbatim, proven) ------
#define FBM 128
#define FBN 128
#define FBKD 8
__global__ __launch_bounds__(256)
void rq_dist_argmin(const float* __restrict__ R, const float* __restrict__ E,
                    const float* __restrict__ rowNorm,
                    unsigned long long* __restrict__ keys)
{
    __shared__ float As[FBKD][FBM];
    __shared__ float Bs[FBKD][FBN];

    const int t  = threadIdx.x;
    const int tx = t & 15;
    const int ty = t >> 4;
    const int rowBase = blockIdx.y * FBM;
    const int colBase = blockIdx.x * FBN;

    const int lm   = t >> 1;
    const int lseg = (t & 1) * 4;

    const float* Aptr = R + (size_t)(rowBase + lm) * D_ + lseg;
    const float* Bptr = E + (size_t)(colBase + lm) * D_ + lseg;

    float acc[8][8];
#pragma unroll
    for (int i = 0; i < 8; ++i)
#pragma unroll
        for (int j = 0; j < 8; ++j) acc[i][j] = 0.0f;

    for (int dt = 0; dt < D_; dt += FBKD) {
        const float4 av = *(const float4*)(Aptr + dt);
        const float4 bv = *(const float4*)(Bptr + dt);
        __syncthreads();
        As[lseg + 0][lm] = av.x; As[lseg + 1][lm] = av.y;
        As[lseg + 2][lm] = av.z; As[lseg + 3][lm] = av.w;
        Bs[lseg + 0][lm] = bv.x; Bs[lseg + 1][lm] = bv.y;
        Bs[lseg + 2][lm] = bv.z; Bs[lseg + 3][lm] = bv.w;
        __syncthreads();
#pragma unroll
        for (int dd = 0; dd < FBKD; ++dd) {
            float a[8], b[8];
            *(float4*)&a[0] = *(const float4*)&As[dd][ty * 4];
            *(float4*)&a[4] = *(const float4*)&As[dd][ty * 4 + 64];
            *(float4*)&b[0] = *(const float4*)&Bs[dd][tx * 4];
            *(float4*)&b[4] = *(const float4*)&Bs[dd][tx * 4 + 64];
#pragma unroll
            for (int i = 0; i < 8; ++i)
#pragma unroll
                for (int j = 0; j < 8; ++j)
                    acc[i][j] = fmaf(a[i], b[j], acc[i][j]);
        }
    }

#pragma unroll
    for (int i = 0; i < 8; ++i) {
        const int rl = ty * 4 + (i & 3) + ((i >= 4) ? 64 : 0);
        const float An = rowNorm[rowBase + rl];
        unsigned long long best = 0xFFFFFFFFFFFFFFFFull;
#pragma unroll
        for (int j = 0; j < 8; ++j) {
            const int col = colBase + tx * 4 + (j & 3) + ((j >= 4) ? 64 : 0);
            const float c = __fsub_rn(An, 2.0f * acc[i][j]);
            const unsigned long long key =
                ((unsigned long long)__float_as_uint(c) << 32)
                | (unsigned int)col;
            if (key < best) best = key;
        }
#pragma unroll
        for (int m = 1; m < 16; m <<= 1) {
            const unsigned long long o = __shfl_xor(best, m, 64);
            if (o < best) best = o;
        }
        if (tx == 0)
            atomicMin(&keys[rowBase + rl], best);
    }
}

// -------- fallback per-layer update (keys-based, round-0 verbatim) --------
__global__ __launch_bounds__(256)
void rq_update(float* __restrict__ R, const float* __restrict__ E,
               unsigned long long* __restrict__ keys,
               float* __restrict__ qout, float* __restrict__ idxOut,
               float* __restrict__ rowNorm, double* __restrict__ lossPartial,
               int layer)
{
    const int wave = threadIdx.x >> 6;
    const int lane = threadIdx.x & 63;
    const int n = blockIdx.x * 4 + wave;
    const unsigned long long key = keys[n];
    const int k = (int)(key & 0xFFFFFFFFull);

    const float4* ep = (const float4*)(E + (size_t)k * D_);
    float4* rp = (float4*)(R + (size_t)n * D_);
    float4* qp = (float4*)(qout + (size_t)n * D_);

    double lsum = 0.0, asum = 0.0;
#pragma unroll
    for (int u = 0; u < 2; ++u) {
        const int idx = u * 64 + lane;
        float4 r4 = rp[idx];
        float4 q4 = ep[idx];
        float4 o4 = (layer == 0) ? make_float4(0.f, 0.f, 0.f, 0.f) : qp[idx];
        float rnew[4], qo[4];
        float rr[4] = {r4.x, r4.y, r4.z, r4.w};
        float qq[4] = {q4.x, q4.y, q4.z, q4.w};
        float oo[4] = {o4.x, o4.y, o4.z, o4.w};
#pragma unroll
        for (int c = 0; c < 4; ++c) {
            const float d1  = __fsub_rn(qq[c], rr[c]);
            const float qst = __fadd_rn(rr[c], d1);
            rnew[c] = __fsub_rn(rr[c], qst);
            qo[c]   = __fadd_rn(oo[c], qst);
            lsum += (double)d1 * (double)d1;
            asum += (double)rnew[c] * (double)rnew[c];
        }
        rp[idx] = make_float4(rnew[0], rnew[1], rnew[2], rnew[3]);
        qp[idx] = make_float4(qo[0], qo[1], qo[2], qo[3]);
    }
#pragma unroll
    for (int off = 32; off > 0; off >>= 1) {
        lsum += __shfl_down(lsum, off, 64);
        asum += __shfl_down(asum, off, 64);
    }
    if (lane == 0) {
        rowNorm[n] = (float)asum;
        keys[n] = 0xFFFFFFFFFFFFFFFFull;
        lossPartial[n] = (layer == 0) ? lsum : (lossPartial[n] + lsum);
        idxOut[(size_t)n * L_ + layer] = (float)k;
    }
}

// -------- finalize: sum 10496 per-row partials, scale ----------
__global__ __launch_bounds__(256)
void rq_finalize(float* __restrict__ lossOut,
                 const double* __restrict__ lossPartial)
{
    __shared__ double ws[4];
    const int t = threadIdx.x;
    double s = 0.0;
    for (int i = t; i < NROWS; i += 256) s += lossPartial[i];
#pragma unroll
    for (int off = 32; off > 0; off >>= 1)
        s += __shfl_down(s, off, 64);
    if ((t & 63) == 0) ws[t >> 6] = s;
    __syncthreads();
    if (t == 0) {
        double tot = ws[0] + ws[1] + ws[2] + ws[3];
        *lossOut = (float)(0.25 * tot / (double)QOUT_ELEMS);
    }
}

extern "C" void kernel_launch(void* const* d_in, const int* in_sizes, int n_in,
                              void* d_out, int out_size, void* d_ws, size_t ws_size,
                              hipStream_t stream)
{
    const float* x  = (const float*)d_in[0];
    const float* cb = (const float*)d_in[1];
    float* out = (float*)d_out;
    char* ws = (char*)d_ws;

    float* R = (float*)(ws + WS_R);
    float* rowNorm = (float*)(ws + WS_ROWNORM);
    unsigned long long* keys = (unsigned long long*)(ws + WS_KEYS);
    double* lossPartial = (double*)(ws + WS_LOSS);

    const bool fast = (ws_size >= (size_t)WS_NEEDED);
    f16* Rh = fast ? (f16*)(ws + WS_RH) : (f16*)nullptr;
    f16* Eh = fast ? (f16*)(ws + WS_EH) : (f16*)nullptr;
    int* candCount = fast ? (int*)(ws + WS_CCNT) : (int*)nullptr;
    float* bmax = fast ? (float*)(ws + WS_BMAX) : (float*)nullptr;
    unsigned long long* candList =
        fast ? (unsigned long long*)(ws + WS_CLIST) : (unsigned long long*)nullptr;

    float* idxOut = out + QOUT_ELEMS + 1;

    rq_init<<<NROWS / 4, 256, 0, stream>>>(x, R, rowNorm, keys, Rh, candCount);
    if (fast)
        rq_cvt_eh<<<(L_ * K_ * D_) / (4 * 256), 256, 0, stream>>>(cb, Eh);

    for (int l = 0; l < L_; ++l) {
        const float* E = cb + (size_t)l * K_ * D_;
        if (fast) {
            dim3 grid(K_ / 128, NROWS / 128);   // (32, 82)
            rq_screen_gemm<<<grid, 256, 0, stream>>>(
                Rh, Eh + (size_t)l * K_ * D_, rowNorm, candCount, candList,
                bmax);
            rq_select_update<<<NROWS / 4, 256, 0, stream>>>(
                candCount, candCount, candList, bmax, R, E, out, idxOut,
                rowNorm, lossPartial, l, Rh);
        } else {
            dim3 grid(K_ / FBN, NROWS / FBM);
            rq_dist_argmin<<<grid, 256, 0, stream>>>(R, E, rowNorm, keys);
            rq_update<<<NROWS / 4, 256, 0, stream>>>(R, E, keys, out, idxOut,
                                                     rowNorm, lossPartial, l);
        }
    }
    rq_finalize<<<1, 256, 0, stream>>>(out + QOUT_ELEMS, lossPartial);
}

// Round 10
// 2396.405 us; speedup vs baseline: 1.6416x; 1.0281x over previous
//
#include <hip/hip_runtime.h>
#include <cstdint>
#include <cstddef>

#define B_    256
#define W_    41
#define D_    512
#define K_    4096
#define L_    8
#define NROWS (B_ * W_)            // 10496
#define QOUT_ELEMS (NROWS * D_)    // 5373952

typedef _Float16 f16;
typedef __attribute__((ext_vector_type(4))) _Float16 f16x4;
typedef __attribute__((ext_vector_type(8))) _Float16 f16x8;
typedef __attribute__((ext_vector_type(4))) float f32x4;

// ---------------- workspace layout (bytes) ----------------
#define WS_R        0u            // 21,495,808
#define WS_ROWNORM  21495808u     //     41,984
#define WS_KEYS     21537792u     //     83,968
#define WS_LOSS     21621760u     //     83,968
#define WS_RH       21705728u     // 10,747,904
#define WS_EH       32453632u     // 33,554,432
#define WS_CCNT     66008064u     //     41,984
#define WS_BMAX     66050048u     //  1,343,488 (NROWS * 32 f32)
#define WS_CLIST    67393536u     // 21,495,808 (NROWS * CAP u64)
#define WS_NEEDED   88889344u

#define CAP 256

// async 16B global->LDS (gfx950). LDS dest must be WAVE-UNIFORM; HW writes
// dest + lane*16. Global src is per-lane. (guide §5 / m97 / m104)
__device__ __forceinline__ void gload_lds16(const void* g, void* l)
{
    __builtin_amdgcn_global_load_lds(
        (const __attribute__((address_space(1))) void*)g,
        (__attribute__((address_space(3))) void*)l, 16, 0, 0);
}

// -------- init: residual = x, rowNorm, arm keys + candidate counters ------
__global__ __launch_bounds__(256)
void rq_init(const float* __restrict__ x, float* __restrict__ R,
             float* __restrict__ rowNorm, unsigned long long* __restrict__ keys,
             f16* __restrict__ Rh, int* __restrict__ candCount)
{
    const int wave = threadIdx.x >> 6;
    const int lane = threadIdx.x & 63;
    const int n = blockIdx.x * 4 + wave;
    const float4* xp = (const float4*)(x + (size_t)n * D_);
    float4* rp = (float4*)(R + (size_t)n * D_);
    double asum = 0.0;
#pragma unroll
    for (int u = 0; u < 2; ++u) {
        const int idx = u * 64 + lane;
        float4 v = xp[idx];
        rp[idx] = v;
        if (Rh) {
            f16x4 hv; hv[0]=(_Float16)v.x; hv[1]=(_Float16)v.y;
            hv[2]=(_Float16)v.z; hv[3]=(_Float16)v.w;
            *(f16x4*)(Rh + (size_t)n * D_ + idx * 4) = hv;
        }
        asum += (double)v.x * v.x + (double)v.y * v.y
              + (double)v.z * v.z + (double)v.w * v.w;
    }
#pragma unroll
    for (int off = 32; off > 0; off >>= 1)
        asum += __shfl_down(asum, off, 64);
    if (lane == 0) {
        rowNorm[n] = (float)asum;
        keys[n] = 0xFFFFFFFFFFFFFFFFull;
        if (candCount) candCount[n] = 0;
    }
}

// -------- codebook fp32 -> f16 (all 8 layers, once) ----------
__global__ __launch_bounds__(256)
void rq_cvt_eh(const float* __restrict__ cb, f16* __restrict__ Eh)
{
    const size_t i = ((size_t)blockIdx.x * 256 + threadIdx.x) * 4;
    float4 v = *(const float4*)(cb + i);
    f16x4 h; h[0]=(_Float16)v.x; h[1]=(_Float16)v.y;
    h[2]=(_Float16)v.z; h[3]=(_Float16)v.w;
    *(f16x4*)(Eh + i) = h;
}

// -------- MFMA screen GEMM + fused candidate emission ----------
// Round-10 change: TRUE counted-vmcnt pipeline (T4). r7/r8/r9 all landed at
// 215-225us with MfmaUtil~8% because every scheme ended each K-iter with an
// implicit s_waitcnt vmcnt(0) (inside __syncthreads) — prefetched loads were
// drained the same iteration they were issued, exposing full L2/HBM latency
// per iter (m218 lesson: counted-vs-drain0 = +38-73%). Now: 3-buffer LDS
// ring, loads issued 2 tiles ahead, per-iter wait is s_waitcnt vmcnt(4)
// (tile t done; t+1/t+2 REMAIN IN FLIGHT across the raw s_barrier); vmcnt(0)
// only at the final tile. WAR: buf[(t+2)%3] was read at iter t-1; those
// ds_reads completed before the iter-t barrier (consumed by MFMA) -> safe.
// MFMA operand VALUES identical to r7/r8/r9 (same chunk map) -> screen
// output unchanged -> exactness preserved.
// Emission: per 128-col block, row max -> bmax[row][blk] AND every col with
// S_acc >= blockmax - tau appended as (bits(S)<<32|col). True winner always
// passes its own block's cut (chain spread + 2*e_f16 < tau); global filter +
// verbatim fp32-chain rescore in rq_select_update restores exactness.
__global__ __launch_bounds__(256)
void rq_screen_gemm(const f16* __restrict__ Rh, const f16* __restrict__ Eh,
                    const float* __restrict__ rowNorm,
                    int* __restrict__ candCount,
                    unsigned long long* __restrict__ candList,
                    float* __restrict__ bmax)
{
    // 3 buffers, buf b at lds + b*16384: A [0,8K), B [8K,16K)
    __shared__ __align__(1024) char lds[49152];
    __shared__ float rmaxW[2][128];
    __shared__ float tauS[128];

    const int t    = threadIdx.x;
    const int lane = t & 63;
    const int wid  = t >> 6;
    const int wr   = (wid >> 1) * 64;     // wave quadrant row
    const int wc   = (wid & 1) * 64;      // wave quadrant col
    const int rowBase = blockIdx.y * 128;
    const int colBase = blockIdx.x * 128;

    const int r16 = lane & 15;
    const int ks  = lane >> 4;            // k-slot 0..3

    if (t < 128)
        tauS[t] = sqrtf(rowNorm[rowBase + t]) * 2.0e-5f + 3.0e-4f;

    // ---- staging geometry (wave-uniform LDS dest, per-lane global src) ----
    // chunk c = wid*128 + i*64 + lane; LDS byte c*16 == row(c>>2)*64 +
    // (c&3)*16 (consistent both sides, rule #21).
    const int wu = __builtin_amdgcn_readfirstlane(wid);

    const int c0 = wu * 128 + lane;       // chunk index, issue 0
    const int r0 = c0 >> 2, k0 = (c0 & 3) * 8;
    const int c1 = c0 + 64;               // issue 1
    const int r1 = c1 >> 2, k1 = (c1 & 3) * 8;

    const f16* const gA0 = Rh + (size_t)(rowBase + r0) * D_ + k0;
    const f16* const gA1 = Rh + (size_t)(rowBase + r1) * D_ + k1;
    const f16* const gB0 = Eh + (size_t)(colBase + r0) * D_ + k0;
    const f16* const gB1 = Eh + (size_t)(colBase + r1) * D_ + k1;

    f32x4 acc[4][4];
#pragma unroll
    for (int i = 0; i < 4; ++i)
#pragma unroll
        for (int j = 0; j < 4; ++j) acc[i][j] = (f32x4){0.f, 0.f, 0.f, 0.f};

    // prologue: stage tiles 0 and 1 (8 loads in flight)
    {
        char* b0 = lds;
        gload_lds16(gA0, b0 + wu * 2048);
        gload_lds16(gA1, b0 + wu * 2048 + 1024);
        gload_lds16(gB0, b0 + 8192 + wu * 2048);
        gload_lds16(gB1, b0 + 8192 + wu * 2048 + 1024);
        char* b1 = lds + 16384;
        gload_lds16(gA0 + 32, b1 + wu * 2048);
        gload_lds16(gA1 + 32, b1 + wu * 2048 + 1024);
        gload_lds16(gB0 + 32, b1 + 8192 + wu * 2048);
        gload_lds16(gB1 + 32, b1 + 8192 + wu * 2048 + 1024);
    }

    int bcur = 0;   // buffer holding tile tt
    int bst  = 2;   // buffer for tile tt+2
    for (int tt = 0; tt < 16; ++tt) {
        // wait: tile tt complete; tiles tt+1 (and tt+2 once issued) stay
        // in flight across the barrier — never drain to 0 in the loop.
        if (tt < 15) asm volatile("s_waitcnt vmcnt(4)" ::: "memory");
        else         asm volatile("s_waitcnt vmcnt(0)" ::: "memory");
        __builtin_amdgcn_s_barrier();
        __builtin_amdgcn_sched_barrier(0);

        char* cur = lds + bcur * 16384;
        f16x8 af[4], bf[4];
#pragma unroll
        for (int mi = 0; mi < 4; ++mi)
            af[mi] = *(const f16x8*)(cur + (wr + mi * 16 + r16) * 64 + ks * 16);
#pragma unroll
        for (int ni = 0; ni < 4; ++ni)
            bf[ni] = *(const f16x8*)(cur + 8192 + (wc + ni * 16 + r16) * 64 + ks * 16);

        // issue tile tt+2 (lands ~2 iterations from now)
        if (tt + 2 < 16) {
            char* dst = lds + bst * 16384;
            const int dt = (tt + 2) * 32;
            gload_lds16(gA0 + dt, dst + wu * 2048);
            gload_lds16(gA1 + dt, dst + wu * 2048 + 1024);
            gload_lds16(gB0 + dt, dst + 8192 + wu * 2048);
            gload_lds16(gB1 + dt, dst + 8192 + wu * 2048 + 1024);
        }

#pragma unroll
        for (int mi = 0; mi < 4; ++mi)
#pragma unroll
            for (int ni = 0; ni < 4; ++ni)
                acc[mi][ni] = __builtin_amdgcn_mfma_f32_16x16x32_f16(
                    af[mi], bf[ni], acc[mi][ni], 0, 0, 0);

        bcur = (bcur == 2) ? 0 : bcur + 1;
        bst  = (bst  == 2) ? 0 : bst  + 1;
    }

    // ---- epilogue: per-row block max + candidate emission ----
    // C/D layout (m89): reg i of lane l -> row (l>>4)*4+i, col l&15
    const int g = lane >> 4;

    float vmax[4][4];
#pragma unroll
    for (int mi = 0; mi < 4; ++mi)
#pragma unroll
        for (int i = 0; i < 4; ++i) {
            float m0 = fmaxf(acc[mi][0][i], acc[mi][1][i]);
            float m1 = fmaxf(acc[mi][2][i], acc[mi][3][i]);
            vmax[mi][i] = fmaxf(m0, m1);
        }
#pragma unroll
    for (int off = 1; off < 16; off <<= 1)
#pragma unroll
        for (int mi = 0; mi < 4; ++mi)
#pragma unroll
            for (int i = 0; i < 4; ++i)
                vmax[mi][i] = fmaxf(vmax[mi][i],
                                    __shfl_xor(vmax[mi][i], off, 64));
    if (r16 == 0) {
#pragma unroll
        for (int mi = 0; mi < 4; ++mi)
#pragma unroll
            for (int i = 0; i < 4; ++i)
                rmaxW[wid & 1][wr + mi * 16 + g * 4 + i] = vmax[mi][i];
    }
    __syncthreads();

    if (t < 128)   // publish per-block row max for the global filter
        bmax[(size_t)(rowBase + t) * 32 + blockIdx.x]
            = fmaxf(rmaxW[0][t], rmaxW[1][t]);

#pragma unroll
    for (int mi = 0; mi < 4; ++mi)
#pragma unroll
        for (int i = 0; i < 4; ++i) {
            const int lrow = wr + mi * 16 + g * 4 + i;
            const float thr = fmaxf(rmaxW[0][lrow], rmaxW[1][lrow])
                              - tauS[lrow];
            const int grow = rowBase + lrow;
#pragma unroll
            for (int ni = 0; ni < 4; ++ni) {
                const float sv = acc[mi][ni][i];
                if (sv >= thr) {
                    const int pos = atomicAdd(&candCount[grow], 1);
                    if (pos < CAP)
                        candList[(size_t)grow * CAP + pos] =
                            ((unsigned long long)__float_as_uint(sv) << 32)
                            | (unsigned int)(colBase + wc + ni * 16 + r16);
                }
            }
        }
}

// -------- exact rescore helper: verbatim ascending-d fp32 fmaf chain ------
__device__ __forceinline__ unsigned long long
rescore_key(const float4* __restrict__ a4, const float* __restrict__ E,
            int col, float An)
{
    const float4* b4 = (const float4*)(E + (size_t)col * D_);
    float acc = 0.f;
    for (int d = 0; d < 128; ++d) {
        const float4 a = a4[d], b = b4[d];
        acc = fmaf(a.x, b.x, acc); acc = fmaf(a.y, b.y, acc);
        acc = fmaf(a.z, b.z, acc); acc = fmaf(a.w, b.w, acc);
    }
    const float c = __fsub_rn(An, 2.0f * acc);
    return ((unsigned long long)__float_as_uint(c) << 32) | (unsigned int)col;
}

// -------- fused select + STE update: one wave per row ----------
// (1) gmax = max over the row's 32 per-block maxes; global filter
//     S >= gmax - tau keeps the true winner (same bound as screen's cut).
// (2) exact rescore of the ~2-6 survivors (verbatim fp32 chain);
//     u64 (c,k) min == np.argmin first-index tie rule.
// (3) STE epilogue identical to the proven rq_update (R row cache-hot).
__global__ __launch_bounds__(256)
void rq_select_update(const int* __restrict__ candCountIn,
                      int* __restrict__ candCount,
                      const unsigned long long* __restrict__ candList,
                      const float* __restrict__ bmax,
                      float* __restrict__ R, const float* __restrict__ E,
                      float* __restrict__ qout, float* __restrict__ idxOut,
                      float* __restrict__ rowNorm,
                      double* __restrict__ lossPartial,
                      int layer, f16* __restrict__ Rh)
{
    const int lane = threadIdx.x & 63;
    const int wv   = threadIdx.x >> 6;
    const int n    = blockIdx.x * 4 + wv;
    const float An = rowNorm[n];
    const float4* a4 = (const float4*)(R + (size_t)n * D_);

    // global row max from the 32 per-block maxes
    float gm = bmax[(size_t)n * 32 + (lane & 31)];
#pragma unroll
    for (int off = 1; off < 32; off <<= 1)
        gm = fmaxf(gm, __shfl_xor(gm, off, 64));
    const float tau = sqrtf(An) * 2.0e-5f + 3.0e-4f;
    const float thr = gm - tau;

    unsigned long long best = 0xFFFFFFFFFFFFFFFFull;
    const int cnt = candCountIn[n];

    if (cnt <= CAP) {
        const unsigned long long* cl = candList + (size_t)n * CAP;
        for (int base = 0; base < cnt; base += 64) {
            const int ci = base + lane;
            if (ci < cnt) {
                const unsigned long long e = cl[ci];
                const float sv = __uint_as_float((unsigned int)(e >> 32));
                if (sv >= thr) {
                    const int col = (int)(e & 0xFFFFFFFFull);
                    const unsigned long long k = rescore_key(a4, E, col, An);
                    if (k < best) best = k;
                }
            }
        }
    } else {
        // correctness-safe fallback: exact scan of all K cols
        for (int col = lane; col < K_; col += 64) {
            const unsigned long long k = rescore_key(a4, E, col, An);
            if (k < best) best = k;
        }
    }
#pragma unroll
    for (int mm = 1; mm < 64; mm <<= 1) {
        const unsigned long long o = __shfl_xor(best, mm, 64);
        if (o < best) best = o;
    }
    const int k = (int)(best & 0xFFFFFFFFull);

    // ---- STE update (verbatim exact fp32 replication) ----
    const float4* ep = (const float4*)(E + (size_t)k * D_);
    float4* rp = (float4*)(R + (size_t)n * D_);
    float4* qp = (float4*)(qout + (size_t)n * D_);

    double lsum = 0.0, asum = 0.0;
#pragma unroll
    for (int u = 0; u < 2; ++u) {
        const int idx = u * 64 + lane;
        float4 r4 = rp[idx];
        float4 q4 = ep[idx];
        float4 o4 = (layer == 0) ? make_float4(0.f, 0.f, 0.f, 0.f) : qp[idx];
        float rnew[4], qo[4];
        float rr[4] = {r4.x, r4.y, r4.z, r4.w};
        float qq[4] = {q4.x, q4.y, q4.z, q4.w};
        float oo[4] = {o4.x, o4.y, o4.z, o4.w};
#pragma unroll
        for (int c = 0; c < 4; ++c) {
            const float d1  = __fsub_rn(qq[c], rr[c]);
            const float qst = __fadd_rn(rr[c], d1);
            rnew[c] = __fsub_rn(rr[c], qst);
            qo[c]   = __fadd_rn(oo[c], qst);
            lsum += (double)d1 * (double)d1;
            asum += (double)rnew[c] * (double)rnew[c];
        }
        rp[idx] = make_float4(rnew[0], rnew[1], rnew[2], rnew[3]);
        qp[idx] = make_float4(qo[0], qo[1], qo[2], qo[3]);
        if (layer < L_ - 1) {
            f16x4 hv; hv[0]=(_Float16)rnew[0]; hv[1]=(_Float16)rnew[1];
            hv[2]=(_Float16)rnew[2]; hv[3]=(_Float16)rnew[3];
            *(f16x4*)(Rh + (size_t)n * D_ + idx * 4) = hv;
        }
    }
#pragma unroll
    for (int off = 32; off > 0; off >>= 1) {
        lsum += __shfl_down(lsum, off, 64);
        asum += __shfl_down(asum, off, 64);
    }
    if (lane == 0) {
        rowNorm[n] = (float)asum;
        candCount[n] = 0;                  // re-arm for next layer
        lossPartial[n] = (layer == 0) ? lsum : (lossPartial[n] + lsum);
        idxOut[(size_t)n * L_ + layer] = (float)k;
    }
}

// -------- FALLBACK distance GEMM + argmin (round-0 verbatim, proven) ------
#define FBM 128
#define FBN 128
#define FBKD 8
__global__ __launch_bounds__(256)
void rq_dist_argmin(const float* __restrict__ R, const float* __restrict__ E,
                    const float* __restrict__ rowNorm,
                    unsigned long long* __restrict__ keys)
{
    __shared__ float As[FBKD][FBM];
    __shared__ float Bs[FBKD][FBN];

    const int t  = threadIdx.x;
    const int tx = t & 15;
    const int ty = t >> 4;
    const int rowBase = blockIdx.y * FBM;
    const int colBase = blockIdx.x * FBN;

    const int lm   = t >> 1;
    const int lseg = (t & 1) * 4;

    const float* Aptr = R + (size_t)(rowBase + lm) * D_ + lseg;
    const float* Bptr = E + (size_t)(colBase + lm) * D_ + lseg;

    float acc[8][8];
#pragma unroll
    for (int i = 0; i < 8; ++i)
#pragma unroll
        for (int j = 0; j < 8; ++j) acc[i][j] = 0.0f;

    for (int dt = 0; dt < D_; dt += FBKD) {
        const float4 av = *(const float4*)(Aptr + dt);
        const float4 bv = *(const float4*)(Bptr + dt);
        __syncthreads();
        As[lseg + 0][lm] = av.x; As[lseg + 1][lm] = av.y;
        As[lseg + 2][lm] = av.z; As[lseg + 3][lm] = av.w;
        Bs[lseg + 0][lm] = bv.x; Bs[lseg + 1][lm] = bv.y;
        Bs[lseg + 2][lm] = bv.z; Bs[lseg + 3][lm] = bv.w;
        __syncthreads();
#pragma unroll
        for (int dd = 0; dd < FBKD; ++dd) {
            float a[8], b[8];
            *(float4*)&a[0] = *(const float4*)&As[dd][ty * 4];
            *(float4*)&a[4] = *(const float4*)&As[dd][ty * 4 + 64];
            *(float4*)&b[0] = *(const float4*)&Bs[dd][tx * 4];
            *(float4*)&b[4] = *(const float4*)&Bs[dd][tx * 4 + 64];
#pragma unroll
            for (int i = 0; i < 8; ++i)
#pragma unroll
                for (int j = 0; j < 8; ++j)
                    acc[i][j] = fmaf(a[i], b[j], acc[i][j]);
        }
    }

#pragma unroll
    for (int i = 0; i < 8; ++i) {
        const int rl = ty * 4 + (i & 3) + ((i >= 4) ? 64 : 0);
        const float An = rowNorm[rowBase + rl];
        unsigned long long best = 0xFFFFFFFFFFFFFFFFull;
#pragma unroll
        for (int j = 0; j < 8; ++j) {
            const int col = colBase + tx * 4 + (j & 3) + ((j >= 4) ? 64 : 0);
            const float c = __fsub_rn(An, 2.0f * acc[i][j]);
            const unsigned long long key =
                ((unsigned long long)__float_as_uint(c) << 32)
                | (unsigned int)col;
            if (key < best) best = key;
        }
#pragma unroll
        for (int m = 1; m < 16; m <<= 1) {
            const unsigned long long o = __shfl_xor(best, m, 64);
            if (o < best) best = o;
        }
        if (tx == 0)
            atomicMin(&keys[rowBase + rl], best);
    }
}

// -------- fallback per-layer update (keys-based, round-0 verbatim) --------
__global__ __launch_bounds__(256)
void rq_update(float* __restrict__ R, const float* __restrict__ E,
               unsigned long long* __restrict__ keys,
               float* __restrict__ qout, float* __restrict__ idxOut,
               float* __restrict__ rowNorm, double* __restrict__ lossPartial,
               int layer)
{
    const int wave = threadIdx.x >> 6;
    const int lane = threadIdx.x & 63;
    const int n = blockIdx.x * 4 + wave;
    const unsigned long long key = keys[n];
    const int k = (int)(key & 0xFFFFFFFFull);

    const float4* ep = (const float4*)(E + (size_t)k * D_);
    float4* rp = (float4*)(R + (size_t)n * D_);
    float4* qp = (float4*)(qout + (size_t)n * D_);

    double lsum = 0.0, asum = 0.0;
#pragma unroll
    for (int u = 0; u < 2; ++u) {
        const int idx = u * 64 + lane;
        float4 r4 = rp[idx];
        float4 q4 = ep[idx];
        float4 o4 = (layer == 0) ? make_float4(0.f, 0.f, 0.f, 0.f) : qp[idx];
        float rnew[4], qo[4];
        float rr[4] = {r4.x, r4.y, r4.z, r4.w};
        float qq[4] = {q4.x, q4.y, q4.z, q4.w};
        float oo[4] = {o4.x, o4.y, o4.z, o4.w};
#pragma unroll
        for (int c = 0; c < 4; ++c) {
            const float d1  = __fsub_rn(qq[c], rr[c]);
            const float qst = __fadd_rn(rr[c], d1);
            rnew[c] = __fsub_rn(rr[c], qst);
            qo[c]   = __fadd_rn(oo[c], qst);
            lsum += (double)d1 * (double)d1;
            asum += (double)rnew[c] * (double)rnew[c];
        }
        rp[idx] = make_float4(rnew[0], rnew[1], rnew[2], rnew[3]);
        qp[idx] = make_float4(qo[0], qo[1], qo[2], qo[3]);
    }
#pragma unroll
    for (int off = 32; off > 0; off >>= 1) {
        lsum += __shfl_down(lsum, off, 64);
        asum += __shfl_down(asum, off, 64);
    }
    if (lane == 0) {
        rowNorm[n] = (float)asum;
        keys[n] = 0xFFFFFFFFFFFFFFFFull;
        lossPartial[n] = (layer == 0) ? lsum : (lossPartial[n] + lsum);
        idxOut[(size_t)n * L_ + layer] = (float)k;
    }
}

// -------- finalize: sum 10496 per-row partials, scale ----------
__global__ __launch_bounds__(256)
void rq_finalize(float* __restrict__ lossOut,
                 const double* __restrict__ lossPartial)
{
    __shared__ double ws[4];
    const int t = threadIdx.x;
    double s = 0.0;
    for (int i = t; i < NROWS; i += 256) s += lossPartial[i];
#pragma unroll
    for (int off = 32; off > 0; off >>= 1)
        s += __shfl_down(s, off, 64);
    if ((t & 63) == 0) ws[t >> 6] = s;
    __syncthreads();
    if (t == 0) {
        double tot = ws[0] + ws[1] + ws[2] + ws[3];
        *lossOut = (float)(0.25 * tot / (double)QOUT_ELEMS);
    }
}

extern "C" void kernel_launch(void* const* d_in, const int* in_sizes, int n_in,
                              void* d_out, int out_size, void* d_ws, size_t ws_size,
                              hipStream_t stream)
{
    const float* x  = (const float*)d_in[0];
    const float* cb = (const float*)d_in[1];
    float* out = (float*)d_out;
    char* ws = (char*)d_ws;

    float* R = (float*)(ws + WS_R);
    float* rowNorm = (float*)(ws + WS_ROWNORM);
    unsigned long long* keys = (unsigned long long*)(ws + WS_KEYS);
    double* lossPartial = (double*)(ws + WS_LOSS);

    const bool fast = (ws_size >= (size_t)WS_NEEDED);
    f16* Rh = fast ? (f16*)(ws + WS_RH) : (f16*)nullptr;
    f16* Eh = fast ? (f16*)(ws + WS_EH) : (f16*)nullptr;
    int* candCount = fast ? (int*)(ws + WS_CCNT) : (int*)nullptr;
    float* bmax = fast ? (float*)(ws + WS_BMAX) : (float*)nullptr;
    unsigned long long* candList =
        fast ? (unsigned long long*)(ws + WS_CLIST) : (unsigned long long*)nullptr;

    float* idxOut = out + QOUT_ELEMS + 1;

    rq_init<<<NROWS / 4, 256, 0, stream>>>(x, R, rowNorm, keys, Rh, candCount);
    if (fast)
        rq_cvt_eh<<<(L_ * K_ * D_) / (4 * 256), 256, 0, stream>>>(cb, Eh);

    for (int l = 0; l < L_; ++l) {
        const float* E = cb + (size_t)l * K_ * D_;
        if (fast) {
            dim3 grid(K_ / 128, NROWS / 128);   // (32, 82)
            rq_screen_gemm<<<grid, 256, 0, stream>>>(
                Rh, Eh + (size_t)l * K_ * D_, rowNorm, candCount, candList,
                bmax);
            rq_select_update<<<NROWS / 4, 256, 0, stream>>>(
                candCount, candCount, candList, bmax, R, E, out, idxOut,
                rowNorm, lossPartial, l, Rh);
        } else {
            dim3 grid(K_ / FBN, NROWS / FBM);
            rq_dist_argmin<<<grid, 256, 0, stream>>>(R, E, rowNorm, keys);
            rq_update<<<NROWS / 4, 256, 0, stream>>>(R, E, keys, out, idxOut,
                                                     rowNorm, lossPartial, l);
        }
    }
    rq_finalize<<<1, 256, 0, stream>>>(out + QOUT_ELEMS, lossPartial);
}

// Round 11
// 1683.247 us; speedup vs baseline: 2.3371x; 1.4237x over previous
//
#include <hip/hip_runtime.h>
#include <cstdint>
#include <cstddef>

#define B_    256
#define W_    41
#define D_    512
#define K_    4096
#define L_    8
#define NROWS (B_ * W_)            // 10496
#define QOUT_ELEMS (NROWS * D_)    // 5373952

typedef _Float16 f16;
typedef __attribute__((ext_vector_type(4))) _Float16 f16x4;
typedef __attribute__((ext_vector_type(8))) _Float16 f16x8;
typedef __attribute__((ext_vector_type(4))) float f32x4;

// ---------------- workspace layout (bytes) ----------------
#define WS_R        0u            // 21,495,808
#define WS_ROWNORM  21495808u     //     41,984
#define WS_KEYS     21537792u     //     83,968
#define WS_LOSS     21621760u     //     83,968
#define WS_RH       21705728u     // 10,747,904
#define WS_EH       32453632u     // 33,554,432
#define WS_CCNT     66008064u     //     41,984
#define WS_BMAX     66050048u     //  1,343,488 (NROWS * 32 f32)
#define WS_CLIST    67393536u     // 21,495,808 (NROWS * CAP u64)
#define WS_NEEDED   88889344u

#define CAP 256

// async 16B global->LDS (gfx950). LDS dest must be WAVE-UNIFORM; HW writes
// dest + lane*16. Global src is per-lane. (guide §5 / m97 / m104)
__device__ __forceinline__ void gload_lds16(const void* g, void* l)
{
    __builtin_amdgcn_global_load_lds(
        (const __attribute__((address_space(1))) void*)g,
        (__attribute__((address_space(3))) void*)l, 16, 0, 0);
}

// -------- init: residual = x, rowNorm, arm keys + candidate counters ------
__global__ __launch_bounds__(256)
void rq_init(const float* __restrict__ x, float* __restrict__ R,
             float* __restrict__ rowNorm, unsigned long long* __restrict__ keys,
             f16* __restrict__ Rh, int* __restrict__ candCount)
{
    const int wave = threadIdx.x >> 6;
    const int lane = threadIdx.x & 63;
    const int n = blockIdx.x * 4 + wave;
    const float4* xp = (const float4*)(x + (size_t)n * D_);
    float4* rp = (float4*)(R + (size_t)n * D_);
    double asum = 0.0;
#pragma unroll
    for (int u = 0; u < 2; ++u) {
        const int idx = u * 64 + lane;
        float4 v = xp[idx];
        rp[idx] = v;
        if (Rh) {
            f16x4 hv; hv[0]=(_Float16)v.x; hv[1]=(_Float16)v.y;
            hv[2]=(_Float16)v.z; hv[3]=(_Float16)v.w;
            *(f16x4*)(Rh + (size_t)n * D_ + idx * 4) = hv;
        }
        asum += (double)v.x * v.x + (double)v.y * v.y
              + (double)v.z * v.z + (double)v.w * v.w;
    }
#pragma unroll
    for (int off = 32; off > 0; off >>= 1)
        asum += __shfl_down(asum, off, 64);
    if (lane == 0) {
        rowNorm[n] = (float)asum;
        keys[n] = 0xFFFFFFFFFFFFFFFFull;
        if (candCount) candCount[n] = 0;
    }
}

// -------- codebook fp32 -> f16 (all 8 layers, once) ----------
__global__ __launch_bounds__(256)
void rq_cvt_eh(const float* __restrict__ cb, f16* __restrict__ Eh)
{
    const size_t i = ((size_t)blockIdx.x * 256 + threadIdx.x) * 4;
    float4 v = *(const float4*)(cb + i);
    f16x4 h; h[0]=(_Float16)v.x; h[1]=(_Float16)v.y;
    h[2]=(_Float16)v.z; h[3]=(_Float16)v.w;
    *(f16x4*)(Eh + i) = h;
}

// -------- MFMA screen GEMM + fused candidate emission ----------
// Round-11 change: LDS-AGGREGATED EMISSION. r8/r9/r10 proved the K-loop
// schedule is NOT the bottleneck (3 structures, all ~210-225us, all idle);
// r4's identical K-loop ran ~75us with a dense-S-store epilogue. The +150us
// is the r7+ emission epilogue: 16 sequential divergent exec-mask clusters
// per thread, each a device-scope atomicAdd(candCount[row]) with a DEPENDENT
// candList store, under same-line contention (32 col-blocks x 16 rows/line).
// Fix: per-candidate atomics go to LDS (ds_add, no global round trip) with a
// 4-slot/row LDS buffer (reusing the drained staging LDS); then ONE global
// atomicAdd per (row,block) reserves a contiguous candList range (128
// concurrent atomics ~= 1-2 round trips total) + plain copies. Overflow
// (>4 in-band cands per row-block, P~6e-4) falls back to the direct-atomic
// path — same candList format, select_update unchanged, exactness untouched.
// K-loop: r10's counted-vmcnt 3-buffer ring kept verbatim.
__global__ __launch_bounds__(256)
void rq_screen_gemm(const f16* __restrict__ Rh, const f16* __restrict__ Eh,
                    const float* __restrict__ rowNorm,
                    int* __restrict__ candCount,
                    unsigned long long* __restrict__ candList,
                    float* __restrict__ bmax)
{
    // 3 buffers, buf b at lds + b*16384: A [0,8K), B [8K,16K)
    // After the K-loop the same LDS is reused as emission scratch:
    //   lcnt  = int[128]            at lds + 0      (512 B)
    //   lbuf  = u64[128][4]         at lds + 512    (4096 B)
    __shared__ __align__(1024) char lds[49152];
    __shared__ float rmaxW[2][128];
    __shared__ float tauS[128];

    const int t    = threadIdx.x;
    const int lane = t & 63;
    const int wid  = t >> 6;
    const int wr   = (wid >> 1) * 64;     // wave quadrant row
    const int wc   = (wid & 1) * 64;      // wave quadrant col
    const int rowBase = blockIdx.y * 128;
    const int colBase = blockIdx.x * 128;

    const int r16 = lane & 15;
    const int ks  = lane >> 4;            // k-slot 0..3

    if (t < 128)
        tauS[t] = sqrtf(rowNorm[rowBase + t]) * 2.0e-5f + 3.0e-4f;

    // ---- staging geometry (wave-uniform LDS dest, per-lane global src) ----
    // chunk c = wid*128 + i*64 + lane; LDS byte c*16 == row(c>>2)*64 +
    // (c&3)*16 (consistent both sides, rule #21).
    const int wu = __builtin_amdgcn_readfirstlane(wid);

    const int c0 = wu * 128 + lane;       // chunk index, issue 0
    const int r0 = c0 >> 2, k0 = (c0 & 3) * 8;
    const int c1 = c0 + 64;               // issue 1
    const int r1 = c1 >> 2, k1 = (c1 & 3) * 8;

    const f16* const gA0 = Rh + (size_t)(rowBase + r0) * D_ + k0;
    const f16* const gA1 = Rh + (size_t)(rowBase + r1) * D_ + k1;
    const f16* const gB0 = Eh + (size_t)(colBase + r0) * D_ + k0;
    const f16* const gB1 = Eh + (size_t)(colBase + r1) * D_ + k1;

    f32x4 acc[4][4];
#pragma unroll
    for (int i = 0; i < 4; ++i)
#pragma unroll
        for (int j = 0; j < 4; ++j) acc[i][j] = (f32x4){0.f, 0.f, 0.f, 0.f};

    // prologue: stage tiles 0 and 1 (8 loads in flight)
    {
        char* b0 = lds;
        gload_lds16(gA0, b0 + wu * 2048);
        gload_lds16(gA1, b0 + wu * 2048 + 1024);
        gload_lds16(gB0, b0 + 8192 + wu * 2048);
        gload_lds16(gB1, b0 + 8192 + wu * 2048 + 1024);
        char* b1 = lds + 16384;
        gload_lds16(gA0 + 32, b1 + wu * 2048);
        gload_lds16(gA1 + 32, b1 + wu * 2048 + 1024);
        gload_lds16(gB0 + 32, b1 + 8192 + wu * 2048);
        gload_lds16(gB1 + 32, b1 + 8192 + wu * 2048 + 1024);
    }

    int bcur = 0;   // buffer holding tile tt
    int bst  = 2;   // buffer for tile tt+2
    for (int tt = 0; tt < 16; ++tt) {
        // wait: tile tt complete; tiles tt+1 (and tt+2 once issued) stay
        // in flight across the barrier — never drain to 0 in the loop.
        if (tt < 15) asm volatile("s_waitcnt vmcnt(4)" ::: "memory");
        else         asm volatile("s_waitcnt vmcnt(0)" ::: "memory");
        __builtin_amdgcn_s_barrier();
        __builtin_amdgcn_sched_barrier(0);

        char* cur = lds + bcur * 16384;
        f16x8 af[4], bf[4];
#pragma unroll
        for (int mi = 0; mi < 4; ++mi)
            af[mi] = *(const f16x8*)(cur + (wr + mi * 16 + r16) * 64 + ks * 16);
#pragma unroll
        for (int ni = 0; ni < 4; ++ni)
            bf[ni] = *(const f16x8*)(cur + 8192 + (wc + ni * 16 + r16) * 64 + ks * 16);

        // issue tile tt+2 (lands ~2 iterations from now)
        if (tt + 2 < 16) {
            char* dst = lds + bst * 16384;
            const int dt = (tt + 2) * 32;
            gload_lds16(gA0 + dt, dst + wu * 2048);
            gload_lds16(gA1 + dt, dst + wu * 2048 + 1024);
            gload_lds16(gB0 + dt, dst + 8192 + wu * 2048);
            gload_lds16(gB1 + dt, dst + 8192 + wu * 2048 + 1024);
        }

#pragma unroll
        for (int mi = 0; mi < 4; ++mi)
#pragma unroll
            for (int ni = 0; ni < 4; ++ni)
                acc[mi][ni] = __builtin_amdgcn_mfma_f32_16x16x32_f16(
                    af[mi], bf[ni], acc[mi][ni], 0, 0, 0);

        bcur = (bcur == 2) ? 0 : bcur + 1;
        bst  = (bst  == 2) ? 0 : bst  + 1;
    }

    // ---- epilogue: per-row block max + LDS-aggregated emission ----
    // C/D layout (m89): reg i of lane l -> row (l>>4)*4+i, col l&15
    const int g = lane >> 4;

    float vmax[4][4];
#pragma unroll
    for (int mi = 0; mi < 4; ++mi)
#pragma unroll
        for (int i = 0; i < 4; ++i) {
            float m0 = fmaxf(acc[mi][0][i], acc[mi][1][i]);
            float m1 = fmaxf(acc[mi][2][i], acc[mi][3][i]);
            vmax[mi][i] = fmaxf(m0, m1);
        }
#pragma unroll
    for (int off = 1; off < 16; off <<= 1)
#pragma unroll
        for (int mi = 0; mi < 4; ++mi)
#pragma unroll
            for (int i = 0; i < 4; ++i)
                vmax[mi][i] = fmaxf(vmax[mi][i],
                                    __shfl_xor(vmax[mi][i], off, 64));
    if (r16 == 0) {
#pragma unroll
        for (int mi = 0; mi < 4; ++mi)
#pragma unroll
            for (int i = 0; i < 4; ++i)
                rmaxW[wid & 1][wr + mi * 16 + g * 4 + i] = vmax[mi][i];
    }
    __syncthreads();   // all waves past MFMA; staging LDS fully drained

    // reuse staging LDS as emission scratch
    int* lcnt = (int*)lds;
    unsigned long long (*lbuf)[4] = (unsigned long long (*)[4])(lds + 512);

    if (t < 128) {
        lcnt[t] = 0;
        // publish per-block row max for the global filter
        bmax[(size_t)(rowBase + t) * 32 + blockIdx.x]
            = fmaxf(rmaxW[0][t], rmaxW[1][t]);
    }
    __syncthreads();

#pragma unroll
    for (int mi = 0; mi < 4; ++mi)
#pragma unroll
        for (int i = 0; i < 4; ++i) {
            const int lrow = wr + mi * 16 + g * 4 + i;
            const float thr = fmaxf(rmaxW[0][lrow], rmaxW[1][lrow])
                              - tauS[lrow];
            const int grow = rowBase + lrow;
#pragma unroll
            for (int ni = 0; ni < 4; ++ni) {
                const float sv = acc[mi][ni][i];
                if (sv >= thr) {
                    const unsigned long long pk =
                        ((unsigned long long)__float_as_uint(sv) << 32)
                        | (unsigned int)(colBase + wc + ni * 16 + r16);
                    const int lp = atomicAdd(&lcnt[lrow], 1);
                    if (lp < 4) {
                        lbuf[lrow][lp] = pk;
                    } else {
                        // rare overflow: direct global emission (old path)
                        const int gp = atomicAdd(&candCount[grow], 1);
                        if (gp < CAP)
                            candList[(size_t)grow * CAP + gp] = pk;
                    }
                }
            }
        }
    __syncthreads();

    // batch flush: ONE global atomic per (row, block), then plain copies
    if (t < 128) {
        int c = lcnt[t]; if (c > 4) c = 4;
        const int grow = rowBase + t;
        const int base = atomicAdd(&candCount[grow], c);
        for (int j = 0; j < c; ++j) {
            const int p = base + j;
            if (p < CAP)
                candList[(size_t)grow * CAP + p] = lbuf[t][j];
        }
    }
}

// -------- exact rescore helper: verbatim ascending-d fp32 fmaf chain ------
__device__ __forceinline__ unsigned long long
rescore_key(const float4* __restrict__ a4, const float* __restrict__ E,
            int col, float An)
{
    const float4* b4 = (const float4*)(E + (size_t)col * D_);
    float acc = 0.f;
    for (int d = 0; d < 128; ++d) {
        const float4 a = a4[d], b = b4[d];
        acc = fmaf(a.x, b.x, acc); acc = fmaf(a.y, b.y, acc);
        acc = fmaf(a.z, b.z, acc); acc = fmaf(a.w, b.w, acc);
    }
    const float c = __fsub_rn(An, 2.0f * acc);
    return ((unsigned long long)__float_as_uint(c) << 32) | (unsigned int)col;
}

// -------- fused select + STE update: one wave per row ----------
// (1) gmax = max over the row's 32 per-block maxes; global filter
//     S >= gmax - tau keeps the true winner (same bound as screen's cut).
// (2) exact rescore of the ~2-6 survivors (verbatim fp32 chain);
//     u64 (c,k) min == np.argmin first-index tie rule.
// (3) STE epilogue identical to the proven rq_update (R row cache-hot).
__global__ __launch_bounds__(256)
void rq_select_update(const int* __restrict__ candCountIn,
                      int* __restrict__ candCount,
                      const unsigned long long* __restrict__ candList,
                      const float* __restrict__ bmax,
                      float* __restrict__ R, const float* __restrict__ E,
                      float* __restrict__ qout, float* __restrict__ idxOut,
                      float* __restrict__ rowNorm,
                      double* __restrict__ lossPartial,
                      int layer, f16* __restrict__ Rh)
{
    const int lane = threadIdx.x & 63;
    const int wv   = threadIdx.x >> 6;
    const int n    = blockIdx.x * 4 + wv;
    const float An = rowNorm[n];
    const float4* a4 = (const float4*)(R + (size_t)n * D_);

    // global row max from the 32 per-block maxes
    float gm = bmax[(size_t)n * 32 + (lane & 31)];
#pragma unroll
    for (int off = 1; off < 32; off <<= 1)
        gm = fmaxf(gm, __shfl_xor(gm, off, 64));
    const float tau = sqrtf(An) * 2.0e-5f + 3.0e-4f;
    const float thr = gm - tau;

    unsigned long long best = 0xFFFFFFFFFFFFFFFFull;
    const int cnt = candCountIn[n];

    if (cnt <= CAP) {
        const unsigned long long* cl = candList + (size_t)n * CAP;
        for (int base = 0; base < cnt; base += 64) {
            const int ci = base + lane;
            if (ci < cnt) {
                const unsigned long long e = cl[ci];
                const float sv = __uint_as_float((unsigned int)(e >> 32));
                if (sv >= thr) {
                    const int col = (int)(e & 0xFFFFFFFFull);
                    const unsigned long long k = rescore_key(a4, E, col, An);
                    if (k < best) best = k;
                }
            }
        }
    } else {
        // correctness-safe fallback: exact scan of all K cols
        for (int col = lane; col < K_; col += 64) {
            const unsigned long long k = rescore_key(a4, E, col, An);
            if (k < best) best = k;
        }
    }
#pragma unroll
    for (int mm = 1; mm < 64; mm <<= 1) {
        const unsigned long long o = __shfl_xor(best, mm, 64);
        if (o < best) best = o;
    }
    const int k = (int)(best & 0xFFFFFFFFull);

    // ---- STE update (verbatim exact fp32 replication) ----
    const float4* ep = (const float4*)(E + (size_t)k * D_);
    float4* rp = (float4*)(R + (size_t)n * D_);
    float4* qp = (float4*)(qout + (size_t)n * D_);

    double lsum = 0.0, asum = 0.0;
#pragma unroll
    for (int u = 0; u < 2; ++u) {
        const int idx = u * 64 + lane;
        float4 r4 = rp[idx];
        float4 q4 = ep[idx];
        float4 o4 = (layer == 0) ? make_float4(0.f, 0.f, 0.f, 0.f) : qp[idx];
        float rnew[4], qo[4];
        float rr[4] = {r4.x, r4.y, r4.z, r4.w};
        float qq[4] = {q4.x, q4.y, q4.z, q4.w};
        float oo[4] = {o4.x, o4.y, o4.z, o4.w};
#pragma unroll
        for (int c = 0; c < 4; ++c) {
            const float d1  = __fsub_rn(qq[c], rr[c]);
            const float qst = __fadd_rn(rr[c], d1);
            rnew[c] = __fsub_rn(rr[c], qst);
            qo[c]   = __fadd_rn(oo[c], qst);
            lsum += (double)d1 * (double)d1;
            asum += (double)rnew[c] * (double)rnew[c];
        }
        rp[idx] = make_float4(rnew[0], rnew[1], rnew[2], rnew[3]);
        qp[idx] = make_float4(qo[0], qo[1], qo[2], qo[3]);
        if (layer < L_ - 1) {
            f16x4 hv; hv[0]=(_Float16)rnew[0]; hv[1]=(_Float16)rnew[1];
            hv[2]=(_Float16)rnew[2]; hv[3]=(_Float16)rnew[3];
            *(f16x4*)(Rh + (size_t)n * D_ + idx * 4) = hv;
        }
    }
#pragma unroll
    for (int off = 32; off > 0; off >>= 1) {
        lsum += __shfl_down(lsum, off, 64);
        asum += __shfl_down(asum, off, 64);
    }
    if (lane == 0) {
        rowNorm[n] = (float)asum;
        candCount[n] = 0;                  // re-arm for next layer
        lossPartial[n] = (layer == 0) ? lsum : (lossPartial[n] + lsum);
        idxOut[(size_t)n * L_ + layer] = (float)k;
    }
}

// -------- FALLBACK distance GEMM + argmin (round-0 verbatim, proven) ------
#define FBM 128
#define FBN 128
#define FBKD 8
__global__ __launch_bounds__(256)
void rq_dist_argmin(const float* __restrict__ R, const float* __restrict__ E,
                    const float* __restrict__ rowNorm,
                    unsigned long long* __restrict__ keys)
{
    __shared__ float As[FBKD][FBM];
    __shared__ float Bs[FBKD][FBN];

    const int t  = threadIdx.x;
    const int tx = t & 15;
    const int ty = t >> 4;
    const int rowBase = blockIdx.y * FBM;
    const int colBase = blockIdx.x * FBN;

    const int lm   = t >> 1;
    const int lseg = (t & 1) * 4;

    const float* Aptr = R + (size_t)(rowBase + lm) * D_ + lseg;
    const float* Bptr = E + (size_t)(colBase + lm) * D_ + lseg;

    float acc[8][8];
#pragma unroll
    for (int i = 0; i < 8; ++i)
#pragma unroll
        for (int j = 0; j < 8; ++j) acc[i][j] = 0.0f;

    for (int dt = 0; dt < D_; dt += FBKD) {
        const float4 av = *(const float4*)(Aptr + dt);
        const float4 bv = *(const float4*)(Bptr + dt);
        __syncthreads();
        As[lseg + 0][lm] = av.x; As[lseg + 1][lm] = av.y;
        As[lseg + 2][lm] = av.z; As[lseg + 3][lm] = av.w;
        Bs[lseg + 0][lm] = bv.x; Bs[lseg + 1][lm] = bv.y;
        Bs[lseg + 2][lm] = bv.z; Bs[lseg + 3][lm] = bv.w;
        __syncthreads();
#pragma unroll
        for (int dd = 0; dd < FBKD; ++dd) {
            float a[8], b[8];
            *(float4*)&a[0] = *(const float4*)&As[dd][ty * 4];
            *(float4*)&a[4] = *(const float4*)&As[dd][ty * 4 + 64];
            *(float4*)&b[0] = *(const float4*)&Bs[dd][tx * 4];
            *(float4*)&b[4] = *(const float4*)&Bs[dd][tx * 4 + 64];
#pragma unroll
            for (int i = 0; i < 8; ++i)
#pragma unroll
                for (int j = 0; j < 8; ++j)
                    acc[i][j] = fmaf(a[i], b[j], acc[i][j]);
        }
    }

#pragma unroll
    for (int i = 0; i < 8; ++i) {
        const int rl = ty * 4 + (i & 3) + ((i >= 4) ? 64 : 0);
        const float An = rowNorm[rowBase + rl];
        unsigned long long best = 0xFFFFFFFFFFFFFFFFull;
#pragma unroll
        for (int j = 0; j < 8; ++j) {
            const int col = colBase + tx * 4 + (j & 3) + ((j >= 4) ? 64 : 0);
            const float c = __fsub_rn(An, 2.0f * acc[i][j]);
            const unsigned long long key =
                ((unsigned long long)__float_as_uint(c) << 32)
                | (unsigned int)col;
            if (key < best) best = key;
        }
#pragma unroll
        for (int m = 1; m < 16; m <<= 1) {
            const unsigned long long o = __shfl_xor(best, m, 64);
            if (o < best) best = o;
        }
        if (tx == 0)
            atomicMin(&keys[rowBase + rl], best);
    }
}

// -------- fallback per-layer update (keys-based, round-0 verbatim) --------
__global__ __launch_bounds__(256)
void rq_update(float* __restrict__ R, const float* __restrict__ E,
               unsigned long long* __restrict__ keys,
               float* __restrict__ qout, float* __restrict__ idxOut,
               float* __restrict__ rowNorm, double* __restrict__ lossPartial,
               int layer)
{
    const int wave = threadIdx.x >> 6;
    const int lane = threadIdx.x & 63;
    const int n = blockIdx.x * 4 + wave;
    const unsigned long long key = keys[n];
    const int k = (int)(key & 0xFFFFFFFFull);

    const float4* ep = (const float4*)(E + (size_t)k * D_);
    float4* rp = (float4*)(R + (size_t)n * D_);
    float4* qp = (float4*)(qout + (size_t)n * D_);

    double lsum = 0.0, asum = 0.0;
#pragma unroll
    for (int u = 0; u < 2; ++u) {
        const int idx = u * 64 + lane;
        float4 r4 = rp[idx];
        float4 q4 = ep[idx];
        float4 o4 = (layer == 0) ? make_float4(0.f, 0.f, 0.f, 0.f) : qp[idx];
        float rnew[4], qo[4];
        float rr[4] = {r4.x, r4.y, r4.z, r4.w};
        float qq[4] = {q4.x, q4.y, q4.z, q4.w};
        float oo[4] = {o4.x, o4.y, o4.z, o4.w};
#pragma unroll
        for (int c = 0; c < 4; ++c) {
            const float d1  = __fsub_rn(qq[c], rr[c]);
            const float qst = __fadd_rn(rr[c], d1);
            rnew[c] = __fsub_rn(rr[c], qst);
            qo[c]   = __fadd_rn(oo[c], qst);
            lsum += (double)d1 * (double)d1;
            asum += (double)rnew[c] * (double)rnew[c];
        }
        rp[idx] = make_float4(rnew[0], rnew[1], rnew[2], rnew[3]);
        qp[idx] = make_float4(qo[0], qo[1], qo[2], qo[3]);
    }
#pragma unroll
    for (int off = 32; off > 0; off >>= 1) {
        lsum += __shfl_down(lsum, off, 64);
        asum += __shfl_down(asum, off, 64);
    }
    if (lane == 0) {
        rowNorm[n] = (float)asum;
        keys[n] = 0xFFFFFFFFFFFFFFFFull;
        lossPartial[n] = (layer == 0) ? lsum : (lossPartial[n] + lsum);
        idxOut[(size_t)n * L_ + layer] = (float)k;
    }
}

// -------- finalize: sum 10496 per-row partials, scale ----------
__global__ __launch_bounds__(256)
void rq_finalize(float* __restrict__ lossOut,
                 const double* __restrict__ lossPartial)
{
    __shared__ double ws[4];
    const int t = threadIdx.x;
    double s = 0.0;
    for (int i = t; i < NROWS; i += 256) s += lossPartial[i];
#pragma unroll
    for (int off = 32; off > 0; off >>= 1)
        s += __shfl_down(s, off, 64);
    if ((t & 63) == 0) ws[t >> 6] = s;
    __syncthreads();
    if (t == 0) {
        double tot = ws[0] + ws[1] + ws[2] + ws[3];
        *lossOut = (float)(0.25 * tot / (double)QOUT_ELEMS);
    }
}

extern "C" void kernel_launch(void* const* d_in, const int* in_sizes, int n_in,
                              void* d_out, int out_size, void* d_ws, size_t ws_size,
                              hipStream_t stream)
{
    const float* x  = (const float*)d_in[0];
    const float* cb = (const float*)d_in[1];
    float* out = (float*)d_out;
    char* ws = (char*)d_ws;

    float* R = (float*)(ws + WS_R);
    float* rowNorm = (float*)(ws + WS_ROWNORM);
    unsigned long long* keys = (unsigned long long*)(ws + WS_KEYS);
    double* lossPartial = (double*)(ws + WS_LOSS);

    const bool fast = (ws_size >= (size_t)WS_NEEDED);
    f16* Rh = fast ? (f16*)(ws + WS_RH) : (f16*)nullptr;
    f16* Eh = fast ? (f16*)(ws + WS_EH) : (f16*)nullptr;
    int* candCount = fast ? (int*)(ws + WS_CCNT) : (int*)nullptr;
    float* bmax = fast ? (float*)(ws + WS_BMAX) : (float*)nullptr;
    unsigned long long* candList =
        fast ? (unsigned long long*)(ws + WS_CLIST) : (unsigned long long*)nullptr;

    float* idxOut = out + QOUT_ELEMS + 1;

    rq_init<<<NROWS / 4, 256, 0, stream>>>(x, R, rowNorm, keys, Rh, candCount);
    if (fast)
        rq_cvt_eh<<<(L_ * K_ * D_) / (4 * 256), 256, 0, stream>>>(cb, Eh);

    for (int l = 0; l < L_; ++l) {
        const float* E = cb + (size_t)l * K_ * D_;
        if (fast) {
            dim3 grid(K_ / 128, NROWS / 128);   // (32, 82)
            rq_screen_gemm<<<grid, 256, 0, stream>>>(
                Rh, Eh + (size_t)l * K_ * D_, rowNorm, candCount, candList,
                bmax);
            rq_select_update<<<NROWS / 4, 256, 0, stream>>>(
                candCount, candCount, candList, bmax, R, E, out, idxOut,
                rowNorm, lossPartial, l, Rh);
        } else {
            dim3 grid(K_ / FBN, NROWS / FBM);
            rq_dist_argmin<<<grid, 256, 0, stream>>>(R, E, rowNorm, keys);
            rq_update<<<NROWS / 4, 256, 0, stream>>>(R, E, keys, out, idxOut,
                                                     rowNorm, lossPartial, l);
        }
    }
    rq_finalize<<<1, 256, 0, stream>>>(out + QOUT_ELEMS, lossPartial);
}